// Round 17
// baseline (870.320 us; speedup 1.0000x reference)
//
#include <hip/hip_runtime.h>
#include <hip/hip_bf16.h>

#define H 256
#define LN_EPS 1e-5f
#define PITCH 264   // bf16 elements per LDS A-row (256 + 8 pad), 528 B
#define PITCHT 132  // bf16 elements per transposed elbuf col (128 + 4), 264 B
#define TE 128      // edges per tile (edge kernel)

typedef __attribute__((ext_vector_type(8))) short bf16x8;   // 8 bf16 = 4 VGPRs
typedef __attribute__((ext_vector_type(4))) float f32x4;    // MFMA 16x16 accum

// ---------- helpers ----------
__device__ __forceinline__ float bf2f(unsigned short u) {
  union { unsigned int i; float f; } v; v.i = ((unsigned int)u) << 16; return v.f;
}
// packed pair: low 16 = a, high 16 = b (RNE, single v_cvt_pk_bf16_f32)
__device__ __forceinline__ unsigned int pack2bf(float a, float b) {
  __hip_bfloat162 t = __float22bfloat162_rn(make_float2(a, b));
  unsigned int u;
  __builtin_memcpy(&u, &t, 4);
  return u;
}
// single value via the same HW cvt (1 instruction, RNE)
__device__ __forceinline__ unsigned short f2bf1(float a) {
  return (unsigned short)pack2bf(a, a);
}

// fp32 register-tiled GEMM core (precompute only)
__device__ __forceinline__ void gemm_tile(const float* __restrict__ sA,
                                          const float* __restrict__ W,
                                          int lane_j, int rg, float acc[8][4]) {
#pragma unroll
  for (int mm = 0; mm < 8; mm++)
#pragma unroll
    for (int cc = 0; cc < 4; cc++) acc[mm][cc] = 0.f;
  for (int k = 0; k < H; k += 4) {
    float tvf[8][4];
#pragma unroll
    for (int mm = 0; mm < 8; mm++)
      *(float4*)&tvf[mm][0] = *(const float4*)&sA[(rg * 8 + mm) * H + k];
#pragma unroll
    for (int kk = 0; kk < 4; kk++) {
      const float* wr = W + (k + kk) * H + lane_j;
      float w0 = wr[0], w1 = wr[64], w2 = wr[128], w3 = wr[192];
#pragma unroll
      for (int mm = 0; mm < 8; mm++) {
        float av = tvf[mm][kk];
        acc[mm][0] = fmaf(av, w0, acc[mm][0]);
        acc[mm][1] = fmaf(av, w1, acc[mm][1]);
        acc[mm][2] = fmaf(av, w2, acc[mm][2]);
        acc[mm][3] = fmaf(av, w3, acc[mm][3]);
      }
    }
  }
}

// ---------- precompute kernels ----------

__global__ void k_detect(const int* __restrict__ ei, int* __restrict__ flag) {
  if (threadIdx.x == 0 && blockIdx.x == 0)
    *flag = (ei[1] == 0 && ei[3] == 0 && ei[5] == 0 && ei[7] == 0) ? 1 : 0;
}

__global__ __launch_bounds__(256) void k_zero(float4* __restrict__ p, int n4) {
  int i = blockIdx.x * 256 + threadIdx.x;
  if (i < n4) p[i] = make_float4(0.f, 0.f, 0.f, 0.f);
}

// dst histogram
__global__ __launch_bounds__(256) void k_hist(
    const void* __restrict__ ei, const int* __restrict__ flag64,
    int* __restrict__ hist, int E) {
  int e = blockIdx.x * 256 + threadIdx.x;
  if (e >= E) return;
  int d = (*flag64) ? (int)((const long long*)ei)[(size_t)E + e]
                    : ((const int*)ei)[(size_t)E + e];
  atomicAdd(&hist[d], 1);
}

// exclusive prefix sum over hist[N] -> cursor[N] (single block, 256 threads)
__global__ __launch_bounds__(256) void k_scan(
    const int* __restrict__ hist, int* __restrict__ cursor, int N) {
  __shared__ int part[256];
  int tid = threadIdx.x;
  int chunk = (N + 255) / 256;
  int s = 0;
  for (int i = 0; i < chunk; i++) {
    int idx = tid * chunk + i;
    if (idx < N) s += hist[idx];
  }
  part[tid] = s;
  __syncthreads();
  for (int off = 1; off < 256; off <<= 1) {
    int v = (tid >= off) ? part[tid - off] : 0;
    __syncthreads();
    part[tid] += v;
    __syncthreads();
  }
  int excl = (tid == 0) ? 0 : part[tid - 1];
  for (int i = 0; i < chunk; i++) {
    int idx = tid * chunk + i;
    if (idx < N) {
      cursor[idx] = excl;
      excl += hist[idx];
    }
  }
}

// scatter edges into dst-sorted order (src, dst, edge_attr)
__global__ __launch_bounds__(256) void k_scatter(
    const void* __restrict__ ei, const int* __restrict__ flag64,
    const float* __restrict__ ea, int* __restrict__ cursor,
    int* __restrict__ srcS, int* __restrict__ dstS, float* __restrict__ eaS, int E) {
  int e = blockIdx.x * 256 + threadIdx.x;
  if (e >= E) return;
  int is64 = *flag64;
  int s = is64 ? (int)((const long long*)ei)[e] : ((const int*)ei)[e];
  int d = is64 ? (int)((const long long*)ei)[(size_t)E + e]
               : ((const int*)ei)[(size_t)E + e];
  int p = atomicAdd(&cursor[d], 1);
  srcS[p] = s;
  dstS[p] = d;
  ((float4*)eaS)[p] = ((const float4*)ea)[e];
}

// writes fp32 h AND the bf16 mirror hbf (consumed by the edge gather)
__global__ __launch_bounds__(256) void k_node_proj(
    const float* __restrict__ x, const int* __restrict__ a,
    const float* __restrict__ w, const float* __restrict__ b,
    float* __restrict__ h, unsigned short* __restrict__ hbf, int N) {
  int node = blockIdx.x;
  int j = threadIdx.x;
  float acc = b[j];
  acc = fmaf(x[node * 3 + 0], w[0 * H + j], acc);
  acc = fmaf(x[node * 3 + 1], w[1 * H + j], acc);
  acc = fmaf(x[node * 3 + 2], w[2 * H + j], acc);
  acc = fmaf((float)a[node], w[3 * H + j], acc);
  float v = fmaxf(acc, 0.f);
  h[(size_t)node * H + j] = v;
  hbf[(size_t)node * H + j] = f2bf1(v);
}

// WtC[l][j][k] = (em_w2 @ lin_w[l])[k][j], bf16 hi plane only
__global__ __launch_bounds__(256, 2) void k_wcomb(
    const float* __restrict__ w2, const float* __restrict__ lin_w,
    unsigned short* __restrict__ wcTh) {
  __shared__ __align__(16) float sA[32 * H];
  int l = blockIdx.x >> 3, tile = blockIdx.x & 7;
  int tid = threadIdx.x;
  const float4* src = (const float4*)(w2 + (size_t)tile * 32 * H);
#pragma unroll
  for (int it = 0; it < 8; it++) {
    int vi = it * 256 + tid;
    *(float4*)&sA[vi * 4] = src[vi];
  }
  __syncthreads();
  int lane_j = tid & 63, rg = tid >> 6;
  float acc[8][4];
  gemm_tile(sA, lin_w + (size_t)l * H * H, lane_j, rg, acc);
  unsigned short* oh = wcTh + (size_t)l * H * H;
#pragma unroll
  for (int cc = 0; cc < 4; cc++) {
    int j = lane_j + 64 * cc;
#pragma unroll
    for (int mm = 0; mm < 8; mm++) {
      int k = tile * 32 + rg * 8 + mm;
      oh[(size_t)j * H + k] = f2bf1(acc[mm][cc]);
    }
  }
}

// beta[l] = em_b2 @ lin_w[l] + lin_b[l]
__global__ __launch_bounds__(256) void k_beta(
    const float* __restrict__ lin_w, const float* __restrict__ lin_b,
    const float* __restrict__ b2, float* __restrict__ beta) {
  int l = blockIdx.x, j = threadIdx.x;
  const float* W = lin_w + (size_t)l * H * H;
  float v = lin_b[l * H + j];
  for (int k = 0; k < H; k++) v = fmaf(b2[k], W[k * H + j], v);
  beta[l * H + j] = v;
}

// out_h[l][n][k] = bf16(in[l][k][n])
__global__ __launch_bounds__(256) void k_transp(
    const float* __restrict__ in, unsigned short* __restrict__ outh) {
  int l = blockIdx.z;
  int kb = blockIdx.x * 64, nb = blockIdx.y * 64;
  int tid = threadIdx.x;
  __shared__ float T[64][65];
  const float* src = in + (size_t)l * H * H;
#pragma unroll
  for (int it = 0; it < 16; it++) {
    int idx = it * 256 + tid;
    int kl = idx >> 6, nl = idx & 63;
    T[kl][nl] = src[(size_t)(kb + kl) * H + nb + nl];
  }
  __syncthreads();
  unsigned short* dh = outh + (size_t)l * H * H;
#pragma unroll
  for (int it = 0; it < 8; it++) {
    int u = it * 256 + tid;
    int nl = u >> 5, k2 = (u & 31) * 2;
    size_t o = (size_t)(nb + nl) * H + kb + k2;
    *(unsigned int*)&dh[o] = pack2bf(T[k2][nl], T[k2 + 1][nl]);
  }
}

// ---------- per-layer MFMA kernels ----------

// Edge (dst-sorted), tile = TE(128) edges x 256 cols, 16 waves x 1024 thr.
// Wave owns ONE col-group x ALL 8 row-groups: acc[8]=32 regs, single
// ah/bhf live -> 64-reg cap of (1024,8) holds -> 2 blk/CU = 32 waves.
// Epilogue windows: R10's 4x(32-row x 1-col) form (R11/R12/R14 resplits all
// raised atomic RMW traffic and regressed -- do not re-split).
// R17: TRANSPOSED bf16 elbuf [col][PITCHT] aliasing the A-tile. Writer packs
// each rg's 4 row-consecutive values into one b64 (8 writes + 16 cvt_pk vs
// 32 b16 writes + 32 cvt); scatter preloads its contiguous 32-row column
// slice as 8 b64 (vs 32 scalar b16 at stride 528B). ~-64 issue slots/thread,
// bit-identical numerics. All accesses 8B-aligned (264B col stride).
__global__ __launch_bounds__(1024, 8) void k_edge_mfma(
    const float* __restrict__ eaS,
    const float* __restrict__ w1, const float* __restrict__ b1,
    const unsigned short* __restrict__ Wth,
    const float* __restrict__ beta,
    const unsigned short* __restrict__ hbf, float* __restrict__ agg,
    const int* __restrict__ srcS, const int* __restrict__ dstS) {
  __shared__ __align__(16) unsigned short sAh[TE * PITCH];  // 67584 B, A-tile / elbufT
  __shared__ __align__(16) float sEA[TE * 4];               // 2048 B
  __shared__ int sSrc[TE];
  __shared__ int sDst[TE];
  int tid = threadIdx.x;
  int base = blockIdx.x * TE;
  if (tid < TE) {
    sSrc[tid] = srcS[base + tid];
  } else if (tid < 2 * TE) {
    sDst[tid - TE] = dstS[base + tid - TE];
  } else if (tid < 3 * TE) {
    int t = tid - 2 * TE;
    ((float4*)sEA)[t] = ((const float4*)(eaS + (size_t)base * 4))[t];
  }
  __syncthreads();
  {  // t = relu(eaS @ w1 + b1) -> bf16 hi plane (col pair, 16 rows/thread)
    int j2 = (tid & 127) * 2;
    int r0 = (tid >> 7) * 16;          // 8 groups x 16 rows = 128 rows
    float wv0[4], wv1[4];
#pragma unroll
    for (int q = 0; q < 4; q++) { wv0[q] = w1[q * H + j2]; wv1[q] = w1[q * H + j2 + 1]; }
    float bb0 = b1[j2], bb1 = b1[j2 + 1];
#pragma unroll
    for (int m = r0; m < r0 + 16; m++) {
      float4 e4 = *(const float4*)&sEA[m * 4];   // one b128 read per row
      float t0 = fmaf(e4.x, wv0[0], bb0);
      float t1 = fmaf(e4.x, wv1[0], bb1);
      t0 = fmaf(e4.y, wv0[1], t0);  t1 = fmaf(e4.y, wv1[1], t1);
      t0 = fmaf(e4.z, wv0[2], t0);  t1 = fmaf(e4.z, wv1[2], t1);
      t0 = fmaf(e4.w, wv0[3], t0);  t1 = fmaf(e4.w, wv1[3], t1);
      *(unsigned int*)&sAh[m * PITCH + j2] = pack2bf(fmaxf(t0, 0.f), fmaxf(t1, 0.f));
    }
  }
  __syncthreads();
  int lane = tid & 63, wv = tid >> 6;           // wv in 0..15 = col-group
  int lane15 = lane & 15, quad = lane >> 4;
  f32x4 acc[8];
#pragma unroll
  for (int i = 0; i < 8; i++) acc[i] = (f32x4){0.f, 0.f, 0.f, 0.f};
  const unsigned short* aph = sAh + lane15 * PITCH + quad * 8;
  const unsigned short* bph = Wth + (size_t)(wv * 16 + lane15) * H + quad * 8;
#pragma unroll
  for (int st = 0; st < 8; st++) {
    bf16x8 bhf = *(const bf16x8*)(bph + st * 32);
#pragma unroll
    for (int rg = 0; rg < 8; rg++) {
      bf16x8 ah = *(const bf16x8*)(aph + rg * 16 * PITCH + st * 32);
      acc[rg] = __builtin_amdgcn_mfma_f32_16x16x32_bf16(ah, bhf, acc[rg], 0, 0, 0);
    }
  }
  float bv = beta[wv * 16 + lane15];
  __syncthreads();  // all waves done reading A; sAh becomes TRANSPOSED elbuf
  // elbufT write: col = wv*16+lane15; rows rg*16+quad*4..+3 are consecutive
  // -> one b64 per rg (2 cvt_pk). acc dies here (never co-live with hvp).
  {
    int col = wv * 16 + lane15;
#pragma unroll
    for (int rg = 0; rg < 8; rg++) {
      uint2 wq;
      wq.x = pack2bf(acc[rg][0] + bv, acc[rg][1] + bv);
      wq.y = pack2bf(acc[rg][2] + bv, acc[rg][3] + bv);
      *(uint2*)&sAh[col * PITCHT + rg * 16 + quad * 4] = wq;
    }
  }
  // coalesced bf16 h-gather: one contiguous 128B run per row per wave;
  // pairs packed with one lshl_or each. Loads drain under the barrier.
  int jcol = tid & 255, quarter = tid >> 8;
  const int* msrc = sSrc + quarter * 32;
  unsigned int hvp[16];
#pragma unroll
  for (int p = 0; p < 16; p++) {
    unsigned int u0 = hbf[(size_t)msrc[2 * p] * H + jcol];
    unsigned int u1 = hbf[(size_t)msrc[2 * p + 1] * H + jcol];
    hvp[p] = u0 | (u1 << 16);
  }
  __syncthreads();
  // scatter: preload this thread's contiguous 32-row column slice (8 b64),
  // then segment-sum over the 32 dst-sorted rows.
  {
    unsigned int ev[16];
#pragma unroll
    for (int k = 0; k < 8; k++)
      *(uint2*)&ev[k * 2] = *(const uint2*)&sAh[jcol * PITCHT + quarter * 32 + k * 4];
    const int* mdst = sDst + quarter * 32;
    float run = 0.f;
    int prev = mdst[0];
#pragma unroll
    for (int m = 0; m < 32; m++) {
      int d = mdst[m];
      unsigned int hp = hvp[m >> 1];
      unsigned short hu = (m & 1) ? (unsigned short)(hp >> 16) : (unsigned short)hp;
      unsigned int ep = ev[m >> 1];
      unsigned short eu = (m & 1) ? (unsigned short)(ep >> 16) : (unsigned short)ep;
      float msg = fmaxf(bf2f(hu) + bf2f(eu), 0.f);
      if (d != prev) {
        atomicAdd(&agg[(size_t)prev * H + jcol], run);
        run = 0.f;
        prev = d;
      }
      run += msg;
    }
    atomicAdd(&agg[(size_t)prev * H + jcol], run);
  }
}

// Node: z=h+agg; z1=relu(z@w1+b1); z2=z1@w2+b2; LN; h += relu(LN).
// 64-row tile, 1024 thr x 16 waves, wave owns ONE 16-col group x ALL 4
// row-groups -> acc[4]=16 regs -> fits 64-reg cap of (1024,8) -> 32 waves/CU.
// last==1 fuses the mean-pool -- thread sums its 16 rows' hn and does one
// atomicAdd into g[graph][col]; h/hbf writes skipped (final h unused).
__global__ __launch_bounds__(1024, 8) void k_node_mfma(
    float* __restrict__ h, unsigned short* __restrict__ hbf,
    const float* __restrict__ agg,
    const unsigned short* __restrict__ w1Th, const float* __restrict__ b1,
    const unsigned short* __restrict__ w2Th, const float* __restrict__ b2,
    const float* __restrict__ lng, const float* __restrict__ lnb,
    float* __restrict__ g, int n, int last) {
  __shared__ __align__(16) unsigned short sAh[64 * PITCH];  // 33792 B
  __shared__ float sPartS[64][16];
  __shared__ float sPartQ[64][16];
  __shared__ float sMu[64];
  __shared__ float sRstd[64];
  int tid = threadIdx.x;
  int base = blockIdx.x * 64;
  const float4* h4 = (const float4*)(h + (size_t)base * H);
  const float4* a4 = (const float4*)(agg + (size_t)base * H);
#pragma unroll
  for (int it = 0; it < 4; it++) {  // all 64 rows (4096 float4)
    int vi = it * 1024 + tid;
    int row = vi >> 6, c4 = (vi & 63) * 4;
    float4 hv = h4[vi], av = a4[vi];
    uint2 uh;
    uh.x = pack2bf(hv.x + av.x, hv.y + av.y);
    uh.y = pack2bf(hv.z + av.z, hv.w + av.w);
    *(uint2*)&sAh[row * PITCH + c4] = uh;
  }
  __syncthreads();
  int lane = tid & 63, wv = tid >> 6;          // wv 0..15 = col-group
  int lane15 = lane & 15, quad = lane >> 4;
  int col = wv * 16 + lane15;                  // this thread's output column
  const unsigned short* aph = sAh + lane15 * PITCH + quad * 8;
  // ---- GEMM1: z1 = relu(z @ w1 + b1), acc[rg]
  f32x4 acc[4];
#pragma unroll
  for (int i = 0; i < 4; i++) acc[i] = (f32x4){0.f, 0.f, 0.f, 0.f};
  {
    const unsigned short* bph = w1Th + (size_t)col * H + quad * 8;
#pragma unroll
    for (int st = 0; st < 8; st++) {
      bf16x8 bhf = *(const bf16x8*)(bph + st * 32);
#pragma unroll
      for (int rg = 0; rg < 4; rg++) {
        bf16x8 ah = *(const bf16x8*)(aph + rg * 16 * PITCH + st * 32);
        acc[rg] = __builtin_amdgcn_mfma_f32_16x16x32_bf16(ah, bhf, acc[rg], 0, 0, 0);
      }
    }
  }
  float b1v = b1[col];
  __syncthreads();  // all waves done reading z
#pragma unroll
  for (int rg = 0; rg < 4; rg++)
#pragma unroll
    for (int r = 0; r < 4; r++) {
      int row = rg * 16 + quad * 4 + r;
      sAh[row * PITCH + col] = f2bf1(fmaxf(acc[rg][r] + b1v, 0.f));
    }
  __syncthreads();
  // ---- GEMM2: z2 = z1 @ w2 + b2, acc2[rg]
  f32x4 acc2[4];
#pragma unroll
  for (int i = 0; i < 4; i++) acc2[i] = (f32x4){0.f, 0.f, 0.f, 0.f};
  {
    const unsigned short* bph = w2Th + (size_t)col * H + quad * 8;
#pragma unroll
    for (int st = 0; st < 8; st++) {
      bf16x8 bhf = *(const bf16x8*)(bph + st * 32);
#pragma unroll
      for (int rg = 0; rg < 4; rg++) {
        bf16x8 ah = *(const bf16x8*)(aph + rg * 16 * PITCH + st * 32);
        acc2[rg] = __builtin_amdgcn_mfma_f32_16x16x32_bf16(ah, bhf, acc2[rg], 0, 0, 0);
      }
    }
  }
  float b2v = b2[col], gv = lng[col], bbv = lnb[col];
  // ---- LN partials: per row, reduce this wave's 16 cols
#pragma unroll
  for (int rg = 0; rg < 4; rg++)
#pragma unroll
    for (int r = 0; r < 4; r++) {
      int row = rg * 16 + quad * 4 + r;
      float z2 = acc2[rg][r] + b2v;
      float s = z2, ss = z2 * z2;
      s += __shfl_xor(s, 1, 64); ss += __shfl_xor(ss, 1, 64);
      s += __shfl_xor(s, 2, 64); ss += __shfl_xor(ss, 2, 64);
      s += __shfl_xor(s, 4, 64); ss += __shfl_xor(ss, 4, 64);
      s += __shfl_xor(s, 8, 64); ss += __shfl_xor(ss, 8, 64);
      if (lane15 == 0) { sPartS[row][wv] = s; sPartQ[row][wv] = ss; }
    }
  __syncthreads();
  if (tid < 64) {
    float s = 0.f, ss = 0.f;
#pragma unroll
    for (int w = 0; w < 16; w++) { s += sPartS[tid][w]; ss += sPartQ[tid][w]; }
    float mu = s * (1.f / H);
    float var = ss * (1.f / H) - mu * mu;
    sMu[tid] = mu;
    sRstd[tid] = rsqrtf(var + LN_EPS);
  }
  __syncthreads();
  // ---- apply LN + residual
  if (!last) {
#pragma unroll
    for (int rg = 0; rg < 4; rg++)
#pragma unroll
      for (int r = 0; r < 4; r++) {
        int row = rg * 16 + quad * 4 + r;
        float mu = sMu[row], rstd = sRstd[row];
        size_t o = (size_t)(base + row) * H + col;
        float z2 = acc2[rg][r] + b2v;
        float v = fmaf((z2 - mu) * rstd, gv, bbv);
        float hn = h[o] + fmaxf(v, 0.f);
        h[o] = hn;
        hbf[o] = f2bf1(hn);
      }
  } else {
    // fused mean-pool: block's 64 rows lie in one graph (64 | n)
    int bg = base / n;
    float psum = 0.f;
#pragma unroll
    for (int rg = 0; rg < 4; rg++)
#pragma unroll
      for (int r = 0; r < 4; r++) {
        int row = rg * 16 + quad * 4 + r;
        float mu = sMu[row], rstd = sRstd[row];
        size_t o = (size_t)(base + row) * H + col;
        float z2 = acc2[rg][r] + b2v;
        float v = fmaf((z2 - mu) * rstd, gv, bbv);
        psum += h[o] + fmaxf(v, 0.f);
      }
    atomicAdd(&g[(size_t)bg * H + col], psum);
  }
}

// Head MLP from pooled g. One block per graph.
__global__ __launch_bounds__(256) void k_head(
    const float* __restrict__ g,
    const float* __restrict__ w1, const float* __restrict__ b1,
    const float* __restrict__ w2, const float* __restrict__ b2,
    float* __restrict__ out, int n) {
  __shared__ float sG[H];
  __shared__ float sT[H];
  __shared__ float sR[4];
  int b = blockIdx.x, tid = threadIdx.x;
  sG[tid] = g[(size_t)b * H + tid] / (float)n;
  __syncthreads();
  float t = b1[tid];
  for (int k = 0; k < H; k++) t = fmaf(sG[k], w1[k * H + tid], t);
  sT[tid] = fmaxf(t, 0.f);
  __syncthreads();
  float p = sT[tid] * w2[tid];
#pragma unroll
  for (int off = 32; off > 0; off >>= 1) p += __shfl_xor(p, off, 64);
  if ((tid & 63) == 0) sR[tid >> 6] = p;
  __syncthreads();
  if (tid == 0) out[b] = sR[0] + sR[1] + sR[2] + sR[3] + b2[0];
}

// ---------- launcher ----------
extern "C" void kernel_launch(void* const* d_in, const int* in_sizes, int n_in,
                              void* d_out, int out_size, void* d_ws, size_t ws_size,
                              hipStream_t stream) {
  const float* x      = (const float*)d_in[0];
  const float* ea     = (const float*)d_in[1];
  const void*  ei     = d_in[2];
  const int*   a      = (const int*)d_in[3];
  const float* np_w   = (const float*)d_in[4];
  const float* np_b   = (const float*)d_in[5];
  const float* em_w1  = (const float*)d_in[6];
  const float* em_b1  = (const float*)d_in[7];
  const float* em_w2  = (const float*)d_in[8];
  const float* em_b2  = (const float*)d_in[9];
  const float* lin_w  = (const float*)d_in[10];
  const float* lin_b  = (const float*)d_in[11];
  const float* m_w1   = (const float*)d_in[12];
  const float* m_b1   = (const float*)d_in[13];
  const float* m_w2   = (const float*)d_in[14];
  const float* m_b2   = (const float*)d_in[15];
  const float* ln_g   = (const float*)d_in[16];
  const float* ln_b   = (const float*)d_in[17];
  const float* hd_w1  = (const float*)d_in[18];
  const float* hd_b1  = (const float*)d_in[19];
  const float* hd_w2  = (const float*)d_in[20];
  const float* hd_b2  = (const float*)d_in[21];

  int N = in_sizes[0] / 3;
  int E = in_sizes[1] / 4;
  int B = out_size;
  int n = N / B;

  // workspace layout
  char* ws = (char*)d_ws;
  size_t off = 0;
  auto alloc = [&](size_t bytes) {
    char* p = ws + off;
    off += (bytes + 255) & ~(size_t)255;
    return p;
  };
  float* h    = (float*)alloc((size_t)N * H * 4);
  unsigned short* hbf = (unsigned short*)alloc((size_t)N * H * 2);
  float* agg  = (float*)alloc((size_t)N * H * 4);
  unsigned short* wcTh = (unsigned short*)alloc((size_t)3 * H * H * 2);
  unsigned short* w1Th = (unsigned short*)alloc((size_t)3 * H * H * 2);
  unsigned short* w2Th = (unsigned short*)alloc((size_t)3 * H * H * 2);
  float* beta  = (float*)alloc(3 * H * 4);
  int*   flag  = (int*)alloc(4);
  int*   hist  = (int*)alloc((size_t)N * 4);
  int*   curs  = (int*)alloc((size_t)N * 4);
  int*   srcS  = (int*)alloc((size_t)E * 4);
  int*   dstS  = (int*)alloc((size_t)E * 4);
  float* eaS   = (float*)alloc((size_t)E * 4 * 4);
  float* g     = (float*)alloc((size_t)B * H * 4);

  float* out = (float*)d_out;
  int ebl = (E + 255) / 256;

  k_detect<<<1, 64, 0, stream>>>((const int*)ei, flag);
  k_zero<<<(N + 1023) / 1024, 256, 0, stream>>>((float4*)hist, N / 4);
  k_hist<<<ebl, 256, 0, stream>>>(ei, flag, hist, E);
  k_scan<<<1, 256, 0, stream>>>(hist, curs, N);
  k_scatter<<<ebl, 256, 0, stream>>>(ei, flag, ea, curs, srcS, dstS, eaS, E);
  k_node_proj<<<N, 256, 0, stream>>>(x, a, np_w, np_b, h, hbf, N);
  k_wcomb<<<24, 256, 0, stream>>>(em_w2, lin_w, wcTh);
  k_beta<<<3, 256, 0, stream>>>(lin_w, lin_b, em_b2, beta);
  k_transp<<<dim3(4, 4, 3), 256, 0, stream>>>(m_w1, w1Th);
  k_transp<<<dim3(4, 4, 3), 256, 0, stream>>>(m_w2, w2Th);

  int n4 = N * H / 4;
  int g4 = B * H / 4;
  k_zero<<<(g4 + 255) / 256, 256, 0, stream>>>((float4*)g, g4);
  for (int l = 0; l < 3; l++) {
    k_zero<<<(n4 + 255) / 256, 256, 0, stream>>>((float4*)agg, n4);
    k_edge_mfma<<<E / TE, 1024, 0, stream>>>(eaS, em_w1, em_b1,
                                             wcTh + (size_t)l * H * H,
                                             beta + (size_t)l * H,
                                             hbf, agg, srcS, dstS);
    k_node_mfma<<<N / 64, 1024, 0, stream>>>(h, hbf, agg,
                                             w1Th + (size_t)l * H * H,
                                             m_b1 + (size_t)l * H,
                                             w2Th + (size_t)l * H * H,
                                             m_b2 + (size_t)l * H,
                                             ln_g + (size_t)l * H, ln_b + (size_t)l * H,
                                             g, n, (l == 2) ? 1 : 0);
  }
  k_head<<<B, 256, 0, stream>>>(g, hd_w1, hd_b1, hd_w2, hd_b2, out, n);
}

// Round 18
// 853.025 us; speedup vs baseline: 1.0203x; 1.0203x over previous
//
#include <hip/hip_runtime.h>
#include <hip/hip_bf16.h>

#define H 256
#define LN_EPS 1e-5f
#define PITCH 264   // bf16 elements per LDS A-row (256 + 8 pad), 528 B
#define PITCHT 132  // bf16 elements per transposed elbuf col (128 + 4), 264 B
#define TE 128      // edges per tile (edge kernel)

typedef __attribute__((ext_vector_type(8))) short bf16x8;   // 8 bf16 = 4 VGPRs
typedef __attribute__((ext_vector_type(4))) float f32x4;    // MFMA 16x16 accum

// ---------- helpers ----------
__device__ __forceinline__ float bf2f(unsigned short u) {
  union { unsigned int i; float f; } v; v.i = ((unsigned int)u) << 16; return v.f;
}
// packed pair: low 16 = a, high 16 = b (RNE, single v_cvt_pk_bf16_f32)
__device__ __forceinline__ unsigned int pack2bf(float a, float b) {
  __hip_bfloat162 t = __float22bfloat162_rn(make_float2(a, b));
  unsigned int u;
  __builtin_memcpy(&u, &t, 4);
  return u;
}
// single value via the same HW cvt (1 instruction, RNE)
__device__ __forceinline__ unsigned short f2bf1(float a) {
  return (unsigned short)pack2bf(a, a);
}

// fp32 register-tiled GEMM core (precompute only)
__device__ __forceinline__ void gemm_tile(const float* __restrict__ sA,
                                          const float* __restrict__ W,
                                          int lane_j, int rg, float acc[8][4]) {
#pragma unroll
  for (int mm = 0; mm < 8; mm++)
#pragma unroll
    for (int cc = 0; cc < 4; cc++) acc[mm][cc] = 0.f;
  for (int k = 0; k < H; k += 4) {
    float tvf[8][4];
#pragma unroll
    for (int mm = 0; mm < 8; mm++)
      *(float4*)&tvf[mm][0] = *(const float4*)&sA[(rg * 8 + mm) * H + k];
#pragma unroll
    for (int kk = 0; kk < 4; kk++) {
      const float* wr = W + (k + kk) * H + lane_j;
      float w0 = wr[0], w1 = wr[64], w2 = wr[128], w3 = wr[192];
#pragma unroll
      for (int mm = 0; mm < 8; mm++) {
        float av = tvf[mm][kk];
        acc[mm][0] = fmaf(av, w0, acc[mm][0]);
        acc[mm][1] = fmaf(av, w1, acc[mm][1]);
        acc[mm][2] = fmaf(av, w2, acc[mm][2]);
        acc[mm][3] = fmaf(av, w3, acc[mm][3]);
      }
    }
  }
}

// ---------- precompute kernels ----------

__global__ void k_detect(const int* __restrict__ ei, int* __restrict__ flag) {
  if (threadIdx.x == 0 && blockIdx.x == 0)
    *flag = (ei[1] == 0 && ei[3] == 0 && ei[5] == 0 && ei[7] == 0) ? 1 : 0;
}

__global__ __launch_bounds__(256) void k_zero(float4* __restrict__ p, int n4) {
  int i = blockIdx.x * 256 + threadIdx.x;
  if (i < n4) p[i] = make_float4(0.f, 0.f, 0.f, 0.f);
}

// dst histogram
__global__ __launch_bounds__(256) void k_hist(
    const void* __restrict__ ei, const int* __restrict__ flag64,
    int* __restrict__ hist, int E) {
  int e = blockIdx.x * 256 + threadIdx.x;
  if (e >= E) return;
  int d = (*flag64) ? (int)((const long long*)ei)[(size_t)E + e]
                    : ((const int*)ei)[(size_t)E + e];
  atomicAdd(&hist[d], 1);
}

// exclusive prefix sum over hist[N] -> cursor[N] (single block, 256 threads)
__global__ __launch_bounds__(256) void k_scan(
    const int* __restrict__ hist, int* __restrict__ cursor, int N) {
  __shared__ int part[256];
  int tid = threadIdx.x;
  int chunk = (N + 255) / 256;
  int s = 0;
  for (int i = 0; i < chunk; i++) {
    int idx = tid * chunk + i;
    if (idx < N) s += hist[idx];
  }
  part[tid] = s;
  __syncthreads();
  for (int off = 1; off < 256; off <<= 1) {
    int v = (tid >= off) ? part[tid - off] : 0;
    __syncthreads();
    part[tid] += v;
    __syncthreads();
  }
  int excl = (tid == 0) ? 0 : part[tid - 1];
  for (int i = 0; i < chunk; i++) {
    int idx = tid * chunk + i;
    if (idx < N) {
      cursor[idx] = excl;
      excl += hist[idx];
    }
  }
}

// scatter edges into dst-sorted order (src, dst, edge_attr)
__global__ __launch_bounds__(256) void k_scatter(
    const void* __restrict__ ei, const int* __restrict__ flag64,
    const float* __restrict__ ea, int* __restrict__ cursor,
    int* __restrict__ srcS, int* __restrict__ dstS, float* __restrict__ eaS, int E) {
  int e = blockIdx.x * 256 + threadIdx.x;
  if (e >= E) return;
  int is64 = *flag64;
  int s = is64 ? (int)((const long long*)ei)[e] : ((const int*)ei)[e];
  int d = is64 ? (int)((const long long*)ei)[(size_t)E + e]
               : ((const int*)ei)[(size_t)E + e];
  int p = atomicAdd(&cursor[d], 1);
  srcS[p] = s;
  dstS[p] = d;
  ((float4*)eaS)[p] = ((const float4*)ea)[e];
}

// writes fp32 h AND the bf16 mirror hbf (consumed by the edge gather)
__global__ __launch_bounds__(256) void k_node_proj(
    const float* __restrict__ x, const int* __restrict__ a,
    const float* __restrict__ w, const float* __restrict__ b,
    float* __restrict__ h, unsigned short* __restrict__ hbf, int N) {
  int node = blockIdx.x;
  int j = threadIdx.x;
  float acc = b[j];
  acc = fmaf(x[node * 3 + 0], w[0 * H + j], acc);
  acc = fmaf(x[node * 3 + 1], w[1 * H + j], acc);
  acc = fmaf(x[node * 3 + 2], w[2 * H + j], acc);
  acc = fmaf((float)a[node], w[3 * H + j], acc);
  float v = fmaxf(acc, 0.f);
  h[(size_t)node * H + j] = v;
  hbf[(size_t)node * H + j] = f2bf1(v);
}

// WtC[l][j][k] = (em_w2 @ lin_w[l])[k][j], bf16 hi plane only
__global__ __launch_bounds__(256, 2) void k_wcomb(
    const float* __restrict__ w2, const float* __restrict__ lin_w,
    unsigned short* __restrict__ wcTh) {
  __shared__ __align__(16) float sA[32 * H];
  int l = blockIdx.x >> 3, tile = blockIdx.x & 7;
  int tid = threadIdx.x;
  const float4* src = (const float4*)(w2 + (size_t)tile * 32 * H);
#pragma unroll
  for (int it = 0; it < 8; it++) {
    int vi = it * 256 + tid;
    *(float4*)&sA[vi * 4] = src[vi];
  }
  __syncthreads();
  int lane_j = tid & 63, rg = tid >> 6;
  float acc[8][4];
  gemm_tile(sA, lin_w + (size_t)l * H * H, lane_j, rg, acc);
  unsigned short* oh = wcTh + (size_t)l * H * H;
#pragma unroll
  for (int cc = 0; cc < 4; cc++) {
    int j = lane_j + 64 * cc;
#pragma unroll
    for (int mm = 0; mm < 8; mm++) {
      int k = tile * 32 + rg * 8 + mm;
      oh[(size_t)j * H + k] = f2bf1(acc[mm][cc]);
    }
  }
}

// beta[l] = em_b2 @ lin_w[l] + lin_b[l]
__global__ __launch_bounds__(256) void k_beta(
    const float* __restrict__ lin_w, const float* __restrict__ lin_b,
    const float* __restrict__ b2, float* __restrict__ beta) {
  int l = blockIdx.x, j = threadIdx.x;
  const float* W = lin_w + (size_t)l * H * H;
  float v = lin_b[l * H + j];
  for (int k = 0; k < H; k++) v = fmaf(b2[k], W[k * H + j], v);
  beta[l * H + j] = v;
}

// out_h[l][n][k] = bf16(in[l][k][n])
__global__ __launch_bounds__(256) void k_transp(
    const float* __restrict__ in, unsigned short* __restrict__ outh) {
  int l = blockIdx.z;
  int kb = blockIdx.x * 64, nb = blockIdx.y * 64;
  int tid = threadIdx.x;
  __shared__ float T[64][65];
  const float* src = in + (size_t)l * H * H;
#pragma unroll
  for (int it = 0; it < 16; it++) {
    int idx = it * 256 + tid;
    int kl = idx >> 6, nl = idx & 63;
    T[kl][nl] = src[(size_t)(kb + kl) * H + nb + nl];
  }
  __syncthreads();
  unsigned short* dh = outh + (size_t)l * H * H;
#pragma unroll
  for (int it = 0; it < 8; it++) {
    int u = it * 256 + tid;
    int nl = u >> 5, k2 = (u & 31) * 2;
    size_t o = (size_t)(nb + nl) * H + kb + k2;
    *(unsigned int*)&dh[o] = pack2bf(T[k2][nl], T[k2 + 1][nl]);
  }
}

// ---------- per-layer MFMA kernels ----------

// Edge (dst-sorted), tile = TE(128) edges x 256 cols, 16 waves x 1024 thr.
// Wave owns ONE col-group x ALL 8 row-groups: acc[8]=32 regs, single
// ah/bhf live -> 64-reg cap of (1024,8) holds -> 2 blk/CU = 32 waves.
// Epilogue windows: R10's 4x(32-row x 1-col) form (R11/R12/R14 resplits all
// raised atomic RMW traffic and regressed -- do not re-split).
// Transposed bf16 elbuf [col][PITCHT] aliasing the A-tile (R17): writer
// packs each rg's 4 row-consecutive values into one b64; scatter preloads
// its contiguous 32-row column slice as 8 b64. Verified 158->153 us.
__global__ __launch_bounds__(1024, 8) void k_edge_mfma(
    const float* __restrict__ eaS,
    const float* __restrict__ w1, const float* __restrict__ b1,
    const unsigned short* __restrict__ Wth,
    const float* __restrict__ beta,
    const unsigned short* __restrict__ hbf, float* __restrict__ agg,
    const int* __restrict__ srcS, const int* __restrict__ dstS) {
  __shared__ __align__(16) unsigned short sAh[TE * PITCH];  // 67584 B, A-tile / elbufT
  __shared__ __align__(16) float sEA[TE * 4];               // 2048 B
  __shared__ int sSrc[TE];
  __shared__ int sDst[TE];
  int tid = threadIdx.x;
  int base = blockIdx.x * TE;
  if (tid < TE) {
    sSrc[tid] = srcS[base + tid];
  } else if (tid < 2 * TE) {
    sDst[tid - TE] = dstS[base + tid - TE];
  } else if (tid < 3 * TE) {
    int t = tid - 2 * TE;
    ((float4*)sEA)[t] = ((const float4*)(eaS + (size_t)base * 4))[t];
  }
  __syncthreads();
  {  // t = relu(eaS @ w1 + b1) -> bf16 hi plane (col pair, 16 rows/thread)
    int j2 = (tid & 127) * 2;
    int r0 = (tid >> 7) * 16;          // 8 groups x 16 rows = 128 rows
    float wv0[4], wv1[4];
#pragma unroll
    for (int q = 0; q < 4; q++) { wv0[q] = w1[q * H + j2]; wv1[q] = w1[q * H + j2 + 1]; }
    float bb0 = b1[j2], bb1 = b1[j2 + 1];
#pragma unroll
    for (int m = r0; m < r0 + 16; m++) {
      float4 e4 = *(const float4*)&sEA[m * 4];   // one b128 read per row
      float t0 = fmaf(e4.x, wv0[0], bb0);
      float t1 = fmaf(e4.x, wv1[0], bb1);
      t0 = fmaf(e4.y, wv0[1], t0);  t1 = fmaf(e4.y, wv1[1], t1);
      t0 = fmaf(e4.z, wv0[2], t0);  t1 = fmaf(e4.z, wv1[2], t1);
      t0 = fmaf(e4.w, wv0[3], t0);  t1 = fmaf(e4.w, wv1[3], t1);
      *(unsigned int*)&sAh[m * PITCH + j2] = pack2bf(fmaxf(t0, 0.f), fmaxf(t1, 0.f));
    }
  }
  __syncthreads();
  int lane = tid & 63, wv = tid >> 6;           // wv in 0..15 = col-group
  int lane15 = lane & 15, quad = lane >> 4;
  f32x4 acc[8];
#pragma unroll
  for (int i = 0; i < 8; i++) acc[i] = (f32x4){0.f, 0.f, 0.f, 0.f};
  const unsigned short* aph = sAh + lane15 * PITCH + quad * 8;
  const unsigned short* bph = Wth + (size_t)(wv * 16 + lane15) * H + quad * 8;
#pragma unroll
  for (int st = 0; st < 8; st++) {
    bf16x8 bhf = *(const bf16x8*)(bph + st * 32);
#pragma unroll
    for (int rg = 0; rg < 8; rg++) {
      bf16x8 ah = *(const bf16x8*)(aph + rg * 16 * PITCH + st * 32);
      acc[rg] = __builtin_amdgcn_mfma_f32_16x16x32_bf16(ah, bhf, acc[rg], 0, 0, 0);
    }
  }
  float bv = beta[wv * 16 + lane15];
  __syncthreads();  // all waves done reading A; sAh becomes TRANSPOSED elbuf
  // elbufT write: col = wv*16+lane15; rows rg*16+quad*4..+3 are consecutive
  // -> one b64 per rg (2 cvt_pk). acc dies here (never co-live with hvp).
  {
    int col = wv * 16 + lane15;
#pragma unroll
    for (int rg = 0; rg < 8; rg++) {
      uint2 wq;
      wq.x = pack2bf(acc[rg][0] + bv, acc[rg][1] + bv);
      wq.y = pack2bf(acc[rg][2] + bv, acc[rg][3] + bv);
      *(uint2*)&sAh[col * PITCHT + rg * 16 + quad * 4] = wq;
    }
  }
  // coalesced bf16 h-gather: one contiguous 128B run per row per wave;
  // pairs packed with one lshl_or each. Loads drain under the barrier.
  int jcol = tid & 255, quarter = tid >> 8;
  const int* msrc = sSrc + quarter * 32;
  unsigned int hvp[16];
#pragma unroll
  for (int p = 0; p < 16; p++) {
    unsigned int u0 = hbf[(size_t)msrc[2 * p] * H + jcol];
    unsigned int u1 = hbf[(size_t)msrc[2 * p + 1] * H + jcol];
    hvp[p] = u0 | (u1 << 16);
  }
  __syncthreads();
  // scatter: preload this thread's contiguous 32-row column slice (8 b64),
  // then segment-sum over the 32 dst-sorted rows.
  {
    unsigned int ev[16];
#pragma unroll
    for (int k = 0; k < 8; k++)
      *(uint2*)&ev[k * 2] = *(const uint2*)&sAh[jcol * PITCHT + quarter * 32 + k * 4];
    const int* mdst = sDst + quarter * 32;
    float run = 0.f;
    int prev = mdst[0];
#pragma unroll
    for (int m = 0; m < 32; m++) {
      int d = mdst[m];
      unsigned int hp = hvp[m >> 1];
      unsigned short hu = (m & 1) ? (unsigned short)(hp >> 16) : (unsigned short)hp;
      unsigned int ep = ev[m >> 1];
      unsigned short eu = (m & 1) ? (unsigned short)(ep >> 16) : (unsigned short)ep;
      float msg = fmaxf(bf2f(hu) + bf2f(eu), 0.f);
      if (d != prev) {
        atomicAdd(&agg[(size_t)prev * H + jcol], run);
        run = 0.f;
        prev = d;
      }
      run += msg;
    }
    atomicAdd(&agg[(size_t)prev * H + jcol], run);
  }
}

// Node: z=h+agg; z1=relu(z@w1+b1); z2=z1@w2+b2; LN; h += relu(LN).
// 64-row tile, 1024 thr x 16 waves, wave owns ONE 16-col group x ALL 4
// row-groups -> acc[4]=16 regs -> fits 64-reg cap of (1024,8) -> 32 waves/CU.
// last==1 fuses the mean-pool -- thread sums its 16 rows' hn and does one
// atomicAdd into g[graph][col]; h/hbf writes skipped (final h unused).
__global__ __launch_bounds__(1024, 8) void k_node_mfma(
    float* __restrict__ h, unsigned short* __restrict__ hbf,
    const float* __restrict__ agg,
    const unsigned short* __restrict__ w1Th, const float* __restrict__ b1,
    const unsigned short* __restrict__ w2Th, const float* __restrict__ b2,
    const float* __restrict__ lng, const float* __restrict__ lnb,
    float* __restrict__ g, int n, int last) {
  __shared__ __align__(16) unsigned short sAh[64 * PITCH];  // 33792 B
  __shared__ float sPartS[64][16];
  __shared__ float sPartQ[64][16];
  __shared__ float sMu[64];
  __shared__ float sRstd[64];
  int tid = threadIdx.x;
  int base = blockIdx.x * 64;
  const float4* h4 = (const float4*)(h + (size_t)base * H);
  const float4* a4 = (const float4*)(agg + (size_t)base * H);
#pragma unroll
  for (int it = 0; it < 4; it++) {  // all 64 rows (4096 float4)
    int vi = it * 1024 + tid;
    int row = vi >> 6, c4 = (vi & 63) * 4;
    float4 hv = h4[vi], av = a4[vi];
    uint2 uh;
    uh.x = pack2bf(hv.x + av.x, hv.y + av.y);
    uh.y = pack2bf(hv.z + av.z, hv.w + av.w);
    *(uint2*)&sAh[row * PITCH + c4] = uh;
  }
  __syncthreads();
  int lane = tid & 63, wv = tid >> 6;          // wv 0..15 = col-group
  int lane15 = lane & 15, quad = lane >> 4;
  int col = wv * 16 + lane15;                  // this thread's output column
  const unsigned short* aph = sAh + lane15 * PITCH + quad * 8;
  // ---- GEMM1: z1 = relu(z @ w1 + b1), acc[rg]
  f32x4 acc[4];
#pragma unroll
  for (int i = 0; i < 4; i++) acc[i] = (f32x4){0.f, 0.f, 0.f, 0.f};
  {
    const unsigned short* bph = w1Th + (size_t)col * H + quad * 8;
#pragma unroll
    for (int st = 0; st < 8; st++) {
      bf16x8 bhf = *(const bf16x8*)(bph + st * 32);
#pragma unroll
      for (int rg = 0; rg < 4; rg++) {
        bf16x8 ah = *(const bf16x8*)(aph + rg * 16 * PITCH + st * 32);
        acc[rg] = __builtin_amdgcn_mfma_f32_16x16x32_bf16(ah, bhf, acc[rg], 0, 0, 0);
      }
    }
  }
  float b1v = b1[col];
  __syncthreads();  // all waves done reading z
#pragma unroll
  for (int rg = 0; rg < 4; rg++)
#pragma unroll
    for (int r = 0; r < 4; r++) {
      int row = rg * 16 + quad * 4 + r;
      sAh[row * PITCH + col] = f2bf1(fmaxf(acc[rg][r] + b1v, 0.f));
    }
  __syncthreads();
  // ---- GEMM2: z2 = z1 @ w2 + b2, acc2[rg]
  f32x4 acc2[4];
#pragma unroll
  for (int i = 0; i < 4; i++) acc2[i] = (f32x4){0.f, 0.f, 0.f, 0.f};
  {
    const unsigned short* bph = w2Th + (size_t)col * H + quad * 8;
#pragma unroll
    for (int st = 0; st < 8; st++) {
      bf16x8 bhf = *(const bf16x8*)(bph + st * 32);
#pragma unroll
      for (int rg = 0; rg < 4; rg++) {
        bf16x8 ah = *(const bf16x8*)(aph + rg * 16 * PITCH + st * 32);
        acc2[rg] = __builtin_amdgcn_mfma_f32_16x16x32_bf16(ah, bhf, acc2[rg], 0, 0, 0);
      }
    }
  }
  float b2v = b2[col], gv = lng[col], bbv = lnb[col];
  // ---- LN partials: per row, reduce this wave's 16 cols
#pragma unroll
  for (int rg = 0; rg < 4; rg++)
#pragma unroll
    for (int r = 0; r < 4; r++) {
      int row = rg * 16 + quad * 4 + r;
      float z2 = acc2[rg][r] + b2v;
      float s = z2, ss = z2 * z2;
      s += __shfl_xor(s, 1, 64); ss += __shfl_xor(ss, 1, 64);
      s += __shfl_xor(s, 2, 64); ss += __shfl_xor(ss, 2, 64);
      s += __shfl_xor(s, 4, 64); ss += __shfl_xor(ss, 4, 64);
      s += __shfl_xor(s, 8, 64); ss += __shfl_xor(ss, 8, 64);
      if (lane15 == 0) { sPartS[row][wv] = s; sPartQ[row][wv] = ss; }
    }
  __syncthreads();
  if (tid < 64) {
    float s = 0.f, ss = 0.f;
#pragma unroll
    for (int w = 0; w < 16; w++) { s += sPartS[tid][w]; ss += sPartQ[tid][w]; }
    float mu = s * (1.f / H);
    float var = ss * (1.f / H) - mu * mu;
    sMu[tid] = mu;
    sRstd[tid] = rsqrtf(var + LN_EPS);
  }
  __syncthreads();
  // ---- apply LN + residual
  if (!last) {
#pragma unroll
    for (int rg = 0; rg < 4; rg++)
#pragma unroll
      for (int r = 0; r < 4; r++) {
        int row = rg * 16 + quad * 4 + r;
        float mu = sMu[row], rstd = sRstd[row];
        size_t o = (size_t)(base + row) * H + col;
        float z2 = acc2[rg][r] + b2v;
        float v = fmaf((z2 - mu) * rstd, gv, bbv);
        float hn = h[o] + fmaxf(v, 0.f);
        h[o] = hn;
        hbf[o] = f2bf1(hn);
      }
  } else {
    // fused mean-pool: block's 64 rows lie in one graph (64 | n)
    int bg = base / n;
    float psum = 0.f;
#pragma unroll
    for (int rg = 0; rg < 4; rg++)
#pragma unroll
      for (int r = 0; r < 4; r++) {
        int row = rg * 16 + quad * 4 + r;
        float mu = sMu[row], rstd = sRstd[row];
        size_t o = (size_t)(base + row) * H + col;
        float z2 = acc2[rg][r] + b2v;
        float v = fmaf((z2 - mu) * rstd, gv, bbv);
        psum += h[o] + fmaxf(v, 0.f);
      }
    atomicAdd(&g[(size_t)bg * H + col], psum);
  }
}

// Head MLP from pooled g. One block per graph.
__global__ __launch_bounds__(256) void k_head(
    const float* __restrict__ g,
    const float* __restrict__ w1, const float* __restrict__ b1,
    const float* __restrict__ w2, const float* __restrict__ b2,
    float* __restrict__ out, int n) {
  __shared__ float sG[H];
  __shared__ float sT[H];
  __shared__ float sR[4];
  int b = blockIdx.x, tid = threadIdx.x;
  sG[tid] = g[(size_t)b * H + tid] / (float)n;
  __syncthreads();
  float t = b1[tid];
  for (int k = 0; k < H; k++) t = fmaf(sG[k], w1[k * H + tid], t);
  sT[tid] = fmaxf(t, 0.f);
  __syncthreads();
  float p = sT[tid] * w2[tid];
#pragma unroll
  for (int off = 32; off > 0; off >>= 1) p += __shfl_xor(p, off, 64);
  if ((tid & 63) == 0) sR[tid >> 6] = p;
  __syncthreads();
  if (tid == 0) out[b] = sR[0] + sR[1] + sR[2] + sR[3] + b2[0];
}

// ---------- launcher ----------
extern "C" void kernel_launch(void* const* d_in, const int* in_sizes, int n_in,
                              void* d_out, int out_size, void* d_ws, size_t ws_size,
                              hipStream_t stream) {
  const float* x      = (const float*)d_in[0];
  const float* ea     = (const float*)d_in[1];
  const void*  ei     = d_in[2];
  const int*   a      = (const int*)d_in[3];
  const float* np_w   = (const float*)d_in[4];
  const float* np_b   = (const float*)d_in[5];
  const float* em_w1  = (const float*)d_in[6];
  const float* em_b1  = (const float*)d_in[7];
  const float* em_w2  = (const float*)d_in[8];
  const float* em_b2  = (const float*)d_in[9];
  const float* lin_w  = (const float*)d_in[10];
  const float* lin_b  = (const float*)d_in[11];
  const float* m_w1   = (const float*)d_in[12];
  const float* m_b1   = (const float*)d_in[13];
  const float* m_w2   = (const float*)d_in[14];
  const float* m_b2   = (const float*)d_in[15];
  const float* ln_g   = (const float*)d_in[16];
  const float* ln_b   = (const float*)d_in[17];
  const float* hd_w1  = (const float*)d_in[18];
  const float* hd_b1  = (const float*)d_in[19];
  const float* hd_w2  = (const float*)d_in[20];
  const float* hd_b2  = (const float*)d_in[21];

  int N = in_sizes[0] / 3;
  int E = in_sizes[1] / 4;
  int B = out_size;
  int n = N / B;

  // workspace layout
  char* ws = (char*)d_ws;
  size_t off = 0;
  auto alloc = [&](size_t bytes) {
    char* p = ws + off;
    off += (bytes + 255) & ~(size_t)255;
    return p;
  };
  float* h    = (float*)alloc((size_t)N * H * 4);
  unsigned short* hbf = (unsigned short*)alloc((size_t)N * H * 2);
  float* agg  = (float*)alloc((size_t)N * H * 4);
  unsigned short* wcTh = (unsigned short*)alloc((size_t)3 * H * H * 2);
  unsigned short* w1Th = (unsigned short*)alloc((size_t)3 * H * H * 2);
  unsigned short* w2Th = (unsigned short*)alloc((size_t)3 * H * H * 2);
  float* beta  = (float*)alloc(3 * H * 4);
  int*   flag  = (int*)alloc(4);
  int*   hist  = (int*)alloc((size_t)N * 4);
  int*   curs  = (int*)alloc((size_t)N * 4);
  int*   srcS  = (int*)alloc((size_t)E * 4);
  int*   dstS  = (int*)alloc((size_t)E * 4);
  float* eaS   = (float*)alloc((size_t)E * 4 * 4);
  float* g     = (float*)alloc((size_t)B * H * 4);

  float* out = (float*)d_out;
  int ebl = (E + 255) / 256;

  k_detect<<<1, 64, 0, stream>>>((const int*)ei, flag);
  hipMemsetAsync(hist, 0, (size_t)N * 4, stream);
  k_hist<<<ebl, 256, 0, stream>>>(ei, flag, hist, E);
  k_scan<<<1, 256, 0, stream>>>(hist, curs, N);
  k_scatter<<<ebl, 256, 0, stream>>>(ei, flag, ea, curs, srcS, dstS, eaS, E);
  k_node_proj<<<N, 256, 0, stream>>>(x, a, np_w, np_b, h, hbf, N);
  k_wcomb<<<24, 256, 0, stream>>>(em_w2, lin_w, wcTh);
  k_beta<<<3, 256, 0, stream>>>(lin_w, lin_b, em_b2, beta);
  k_transp<<<dim3(4, 4, 3), 256, 0, stream>>>(m_w1, w1Th);
  k_transp<<<dim3(4, 4, 3), 256, 0, stream>>>(m_w2, w2Th);

  hipMemsetAsync(g, 0, (size_t)B * H * 4, stream);
  for (int l = 0; l < 3; l++) {
    hipMemsetAsync(agg, 0, (size_t)N * H * 4, stream);
    k_edge_mfma<<<E / TE, 1024, 0, stream>>>(eaS, em_w1, em_b1,
                                             wcTh + (size_t)l * H * H,
                                             beta + (size_t)l * H,
                                             hbf, agg, srcS, dstS);
    k_node_mfma<<<N / 64, 1024, 0, stream>>>(h, hbf, agg,
                                             w1Th + (size_t)l * H * H,
                                             m_b1 + (size_t)l * H,
                                             w2Th + (size_t)l * H * H,
                                             m_b2 + (size_t)l * H,
                                             ln_g + (size_t)l * H, ln_b + (size_t)l * H,
                                             g, n, (l == 2) ? 1 : 0);
  }
  k_head<<<B, 256, 0, stream>>>(g, hd_w1, hd_b1, hd_w2, hd_b2, out, n);
}

// Round 19
// 843.459 us; speedup vs baseline: 1.0318x; 1.0113x over previous
//
#include <hip/hip_runtime.h>
#include <hip/hip_bf16.h>

#define H 256
#define LN_EPS 1e-5f
#define PITCH 264   // bf16 elements per LDS A-row (256 + 8 pad), 528 B
#define PITCHT 132  // bf16 elements per transposed elbuf col (128 + 4), 264 B
#define TE 128      // edges per tile (edge kernel)

typedef __attribute__((ext_vector_type(8))) short bf16x8;   // 8 bf16 = 4 VGPRs
typedef __attribute__((ext_vector_type(4))) float f32x4;    // MFMA 16x16 accum

// ---------- helpers ----------
__device__ __forceinline__ float bf2f(unsigned short u) {
  union { unsigned int i; float f; } v; v.i = ((unsigned int)u) << 16; return v.f;
}
// packed pair: low 16 = a, high 16 = b (RNE, single v_cvt_pk_bf16_f32)
__device__ __forceinline__ unsigned int pack2bf(float a, float b) {
  __hip_bfloat162 t = __float22bfloat162_rn(make_float2(a, b));
  unsigned int u;
  __builtin_memcpy(&u, &t, 4);
  return u;
}
// single value via the same HW cvt (1 instruction, RNE)
__device__ __forceinline__ unsigned short f2bf1(float a) {
  return (unsigned short)pack2bf(a, a);
}
// 64-bit edge_index detection: high words of first 4 long longs are zero
__device__ __forceinline__ int ei_is64(const void* ei) {
  const int* p = (const int*)ei;
  return (p[1] == 0 && p[3] == 0 && p[5] == 0 && p[7] == 0) ? 1 : 0;
}

// fp32 register-tiled GEMM core (precompute only)
__device__ __forceinline__ void gemm_tile(const float* __restrict__ sA,
                                          const float* __restrict__ W,
                                          int lane_j, int rg, float acc[8][4]) {
#pragma unroll
  for (int mm = 0; mm < 8; mm++)
#pragma unroll
    for (int cc = 0; cc < 4; cc++) acc[mm][cc] = 0.f;
  for (int k = 0; k < H; k += 4) {
    float tvf[8][4];
#pragma unroll
    for (int mm = 0; mm < 8; mm++)
      *(float4*)&tvf[mm][0] = *(const float4*)&sA[(rg * 8 + mm) * H + k];
#pragma unroll
    for (int kk = 0; kk < 4; kk++) {
      const float* wr = W + (k + kk) * H + lane_j;
      float w0 = wr[0], w1 = wr[64], w2 = wr[128], w3 = wr[192];
#pragma unroll
      for (int mm = 0; mm < 8; mm++) {
        float av = tvf[mm][kk];
        acc[mm][0] = fmaf(av, w0, acc[mm][0]);
        acc[mm][1] = fmaf(av, w1, acc[mm][1]);
        acc[mm][2] = fmaf(av, w2, acc[mm][2]);
        acc[mm][3] = fmaf(av, w3, acc[mm][3]);
      }
    }
  }
}

// ---------- precompute kernels ----------

// dst histogram (inline 64-bit detection; uniform branch, L2-cached reads)
__global__ __launch_bounds__(256) void k_hist(
    const void* __restrict__ ei, int* __restrict__ hist, int E) {
  int e = blockIdx.x * 256 + threadIdx.x;
  if (e >= E) return;
  int d = ei_is64(ei) ? (int)((const long long*)ei)[(size_t)E + e]
                      : ((const int*)ei)[(size_t)E + e];
  atomicAdd(&hist[d], 1);
}

// exclusive prefix sum over hist[N] -> cursor[N] (single block, 256 threads)
__global__ __launch_bounds__(256) void k_scan(
    const int* __restrict__ hist, int* __restrict__ cursor, int N) {
  __shared__ int part[256];
  int tid = threadIdx.x;
  int chunk = (N + 255) / 256;
  int s = 0;
  for (int i = 0; i < chunk; i++) {
    int idx = tid * chunk + i;
    if (idx < N) s += hist[idx];
  }
  part[tid] = s;
  __syncthreads();
  for (int off = 1; off < 256; off <<= 1) {
    int v = (tid >= off) ? part[tid - off] : 0;
    __syncthreads();
    part[tid] += v;
    __syncthreads();
  }
  int excl = (tid == 0) ? 0 : part[tid - 1];
  for (int i = 0; i < chunk; i++) {
    int idx = tid * chunk + i;
    if (idx < N) {
      cursor[idx] = excl;
      excl += hist[idx];
    }
  }
}

// scatter edges into dst-sorted order (src, dst, edge_attr)
__global__ __launch_bounds__(256) void k_scatter(
    const void* __restrict__ ei,
    const float* __restrict__ ea, int* __restrict__ cursor,
    int* __restrict__ srcS, int* __restrict__ dstS, float* __restrict__ eaS, int E) {
  int e = blockIdx.x * 256 + threadIdx.x;
  if (e >= E) return;
  int is64 = ei_is64(ei);
  int s = is64 ? (int)((const long long*)ei)[e] : ((const int*)ei)[e];
  int d = is64 ? (int)((const long long*)ei)[(size_t)E + e]
               : ((const int*)ei)[(size_t)E + e];
  int p = atomicAdd(&cursor[d], 1);
  srcS[p] = s;
  dstS[p] = d;
  ((float4*)eaS)[p] = ((const float4*)ea)[e];
}

// writes fp32 h AND the bf16 mirror hbf (consumed by the edge gather)
__global__ __launch_bounds__(256) void k_node_proj(
    const float* __restrict__ x, const int* __restrict__ a,
    const float* __restrict__ w, const float* __restrict__ b,
    float* __restrict__ h, unsigned short* __restrict__ hbf, int N) {
  int node = blockIdx.x;
  int j = threadIdx.x;
  float acc = b[j];
  acc = fmaf(x[node * 3 + 0], w[0 * H + j], acc);
  acc = fmaf(x[node * 3 + 1], w[1 * H + j], acc);
  acc = fmaf(x[node * 3 + 2], w[2 * H + j], acc);
  acc = fmaf((float)a[node], w[3 * H + j], acc);
  float v = fmaxf(acc, 0.f);
  h[(size_t)node * H + j] = v;
  hbf[(size_t)node * H + j] = f2bf1(v);
}

// R19 merged precompute: one dispatch, per-block uniform path.
//   bid  0..23 : wcomb  (WtC[l][j][k] = (em_w2 @ lin_w[l])[k][j], bf16 hi)
//   bid 24..26 : beta   (beta[l] = em_b2 @ lin_w[l] + lin_b[l])
//   bid 27..74 : transp m_w1 -> w1Th  (out[l][n][k] = bf16(in[l][k][n]))
//   bid 75..122: transp m_w2 -> w2Th
// Each block takes exactly one path; __syncthreads inside a taken path is
// legal. Shared 32KB buffer covers wcomb staging (32*H f32) and the
// transpose tile (64x65 f32).
__global__ __launch_bounds__(256, 2) void k_prep(
    const float* __restrict__ em_w2, const float* __restrict__ lin_w,
    const float* __restrict__ lin_b, const float* __restrict__ em_b2,
    const float* __restrict__ m_w1, const float* __restrict__ m_w2,
    unsigned short* __restrict__ wcTh, unsigned short* __restrict__ w1Th,
    unsigned short* __restrict__ w2Th, float* __restrict__ beta) {
  __shared__ __align__(16) float sBuf[32 * H];   // 32768 B
  int bid = blockIdx.x;
  int tid = threadIdx.x;
  if (bid < 24) {
    int l = bid >> 3, tile = bid & 7;
    const float4* src = (const float4*)(em_w2 + (size_t)tile * 32 * H);
#pragma unroll
    for (int it = 0; it < 8; it++) {
      int vi = it * 256 + tid;
      *(float4*)&sBuf[vi * 4] = src[vi];
    }
    __syncthreads();
    int lane_j = tid & 63, rg = tid >> 6;
    float acc[8][4];
    gemm_tile(sBuf, lin_w + (size_t)l * H * H, lane_j, rg, acc);
    unsigned short* oh = wcTh + (size_t)l * H * H;
#pragma unroll
    for (int cc = 0; cc < 4; cc++) {
      int j = lane_j + 64 * cc;
#pragma unroll
      for (int mm = 0; mm < 8; mm++) {
        int k = tile * 32 + rg * 8 + mm;
        oh[(size_t)j * H + k] = f2bf1(acc[mm][cc]);
      }
    }
  } else if (bid < 27) {
    int l = bid - 24, j = tid;
    const float* W = lin_w + (size_t)l * H * H;
    float v = lin_b[l * H + j];
    for (int k = 0; k < H; k++) v = fmaf(em_b2[k], W[k * H + j], v);
    beta[l * H + j] = v;
  } else {
    int idx = bid - 27;
    const float* in = m_w1;
    unsigned short* outp = w1Th;
    if (idx >= 48) { idx -= 48; in = m_w2; outp = w2Th; }
    int l = idx >> 4, rem = idx & 15;
    int kb = (rem & 3) * 64, nb = (rem >> 2) * 64;
    float (*T)[65] = (float(*)[65])sBuf;         // 16640 B < 32768 B
    const float* src = in + (size_t)l * H * H;
#pragma unroll
    for (int it = 0; it < 16; it++) {
      int i2 = it * 256 + tid;
      int kl = i2 >> 6, nl = i2 & 63;
      T[kl][nl] = src[(size_t)(kb + kl) * H + nb + nl];
    }
    __syncthreads();
    unsigned short* dh = outp + (size_t)l * H * H;
#pragma unroll
    for (int it = 0; it < 8; it++) {
      int u = it * 256 + tid;
      int nl = u >> 5, k2 = (u & 31) * 2;
      size_t o = (size_t)(nb + nl) * H + kb + k2;
      *(unsigned int*)&dh[o] = pack2bf(T[k2][nl], T[k2 + 1][nl]);
    }
  }
}

// ---------- per-layer MFMA kernels ----------

// Edge (dst-sorted), tile = TE(128) edges x 256 cols, 16 waves x 1024 thr.
// Wave owns ONE col-group x ALL 8 row-groups: acc[8]=32 regs, single
// ah/bhf live -> 64-reg cap of (1024,8) holds -> 2 blk/CU = 32 waves.
// Epilogue windows: R10's 4x(32-row x 1-col) form (R11/R12/R14 resplits all
// raised atomic RMW traffic and regressed -- do not re-split).
// Transposed bf16 elbuf [col][PITCHT] aliasing the A-tile (R17): writer
// packs each rg's 4 row-consecutive values into one b64; scatter preloads
// its contiguous 32-row column slice as 8 b64. Verified 158->153 us.
__global__ __launch_bounds__(1024, 8) void k_edge_mfma(
    const float* __restrict__ eaS,
    const float* __restrict__ w1, const float* __restrict__ b1,
    const unsigned short* __restrict__ Wth,
    const float* __restrict__ beta,
    const unsigned short* __restrict__ hbf, float* __restrict__ agg,
    const int* __restrict__ srcS, const int* __restrict__ dstS) {
  __shared__ __align__(16) unsigned short sAh[TE * PITCH];  // 67584 B, A-tile / elbufT
  __shared__ __align__(16) float sEA[TE * 4];               // 2048 B
  __shared__ int sSrc[TE];
  __shared__ int sDst[TE];
  int tid = threadIdx.x;
  int base = blockIdx.x * TE;
  if (tid < TE) {
    sSrc[tid] = srcS[base + tid];
  } else if (tid < 2 * TE) {
    sDst[tid - TE] = dstS[base + tid - TE];
  } else if (tid < 3 * TE) {
    int t = tid - 2 * TE;
    ((float4*)sEA)[t] = ((const float4*)(eaS + (size_t)base * 4))[t];
  }
  __syncthreads();
  {  // t = relu(eaS @ w1 + b1) -> bf16 hi plane (col pair, 16 rows/thread)
    int j2 = (tid & 127) * 2;
    int r0 = (tid >> 7) * 16;          // 8 groups x 16 rows = 128 rows
    float wv0[4], wv1[4];
#pragma unroll
    for (int q = 0; q < 4; q++) { wv0[q] = w1[q * H + j2]; wv1[q] = w1[q * H + j2 + 1]; }
    float bb0 = b1[j2], bb1 = b1[j2 + 1];
#pragma unroll
    for (int m = r0; m < r0 + 16; m++) {
      float4 e4 = *(const float4*)&sEA[m * 4];   // one b128 read per row
      float t0 = fmaf(e4.x, wv0[0], bb0);
      float t1 = fmaf(e4.x, wv1[0], bb1);
      t0 = fmaf(e4.y, wv0[1], t0);  t1 = fmaf(e4.y, wv1[1], t1);
      t0 = fmaf(e4.z, wv0[2], t0);  t1 = fmaf(e4.z, wv1[2], t1);
      t0 = fmaf(e4.w, wv0[3], t0);  t1 = fmaf(e4.w, wv1[3], t1);
      *(unsigned int*)&sAh[m * PITCH + j2] = pack2bf(fmaxf(t0, 0.f), fmaxf(t1, 0.f));
    }
  }
  __syncthreads();
  int lane = tid & 63, wv = tid >> 6;           // wv in 0..15 = col-group
  int lane15 = lane & 15, quad = lane >> 4;
  f32x4 acc[8];
#pragma unroll
  for (int i = 0; i < 8; i++) acc[i] = (f32x4){0.f, 0.f, 0.f, 0.f};
  const unsigned short* aph = sAh + lane15 * PITCH + quad * 8;
  const unsigned short* bph = Wth + (size_t)(wv * 16 + lane15) * H + quad * 8;
#pragma unroll
  for (int st = 0; st < 8; st++) {
    bf16x8 bhf = *(const bf16x8*)(bph + st * 32);
#pragma unroll
    for (int rg = 0; rg < 8; rg++) {
      bf16x8 ah = *(const bf16x8*)(aph + rg * 16 * PITCH + st * 32);
      acc[rg] = __builtin_amdgcn_mfma_f32_16x16x32_bf16(ah, bhf, acc[rg], 0, 0, 0);
    }
  }
  float bv = beta[wv * 16 + lane15];
  __syncthreads();  // all waves done reading A; sAh becomes TRANSPOSED elbuf
  // elbufT write: col = wv*16+lane15; rows rg*16+quad*4..+3 are consecutive
  // -> one b64 per rg (2 cvt_pk). acc dies here (never co-live with hvp).
  {
    int col = wv * 16 + lane15;
#pragma unroll
    for (int rg = 0; rg < 8; rg++) {
      uint2 wq;
      wq.x = pack2bf(acc[rg][0] + bv, acc[rg][1] + bv);
      wq.y = pack2bf(acc[rg][2] + bv, acc[rg][3] + bv);
      *(uint2*)&sAh[col * PITCHT + rg * 16 + quad * 4] = wq;
    }
  }
  // coalesced bf16 h-gather: one contiguous 128B run per row per wave;
  // pairs packed with one lshl_or each. Loads drain under the barrier.
  int jcol = tid & 255, quarter = tid >> 8;
  const int* msrc = sSrc + quarter * 32;
  unsigned int hvp[16];
#pragma unroll
  for (int p = 0; p < 16; p++) {
    unsigned int u0 = hbf[(size_t)msrc[2 * p] * H + jcol];
    unsigned int u1 = hbf[(size_t)msrc[2 * p + 1] * H + jcol];
    hvp[p] = u0 | (u1 << 16);
  }
  __syncthreads();
  // scatter: preload this thread's contiguous 32-row column slice (8 b64),
  // then segment-sum over the 32 dst-sorted rows.
  {
    unsigned int ev[16];
#pragma unroll
    for (int k = 0; k < 8; k++)
      *(uint2*)&ev[k * 2] = *(const uint2*)&sAh[jcol * PITCHT + quarter * 32 + k * 4];
    const int* mdst = sDst + quarter * 32;
    float run = 0.f;
    int prev = mdst[0];
#pragma unroll
    for (int m = 0; m < 32; m++) {
      int d = mdst[m];
      unsigned int hp = hvp[m >> 1];
      unsigned short hu = (m & 1) ? (unsigned short)(hp >> 16) : (unsigned short)hp;
      unsigned int ep = ev[m >> 1];
      unsigned short eu = (m & 1) ? (unsigned short)(ep >> 16) : (unsigned short)ep;
      float msg = fmaxf(bf2f(hu) + bf2f(eu), 0.f);
      if (d != prev) {
        atomicAdd(&agg[(size_t)prev * H + jcol], run);
        run = 0.f;
        prev = d;
      }
      run += msg;
    }
    atomicAdd(&agg[(size_t)prev * H + jcol], run);
  }
}

// Node: z=h+agg; z1=relu(z@w1+b1); z2=z1@w2+b2; LN; h += relu(LN).
// 64-row tile, 1024 thr x 16 waves, wave owns ONE 16-col group x ALL 4
// row-groups -> acc[4]=16 regs -> fits 64-reg cap of (1024,8) -> 32 waves/CU.
// last==1 fuses the mean-pool -- thread sums its 16 rows' hn and does one
// atomicAdd into g[graph][col]; h/hbf writes skipped (final h unused).
__global__ __launch_bounds__(1024, 8) void k_node_mfma(
    float* __restrict__ h, unsigned short* __restrict__ hbf,
    const float* __restrict__ agg,
    const unsigned short* __restrict__ w1Th, const float* __restrict__ b1,
    const unsigned short* __restrict__ w2Th, const float* __restrict__ b2,
    const float* __restrict__ lng, const float* __restrict__ lnb,
    float* __restrict__ g, int n, int last) {
  __shared__ __align__(16) unsigned short sAh[64 * PITCH];  // 33792 B
  __shared__ float sPartS[64][16];
  __shared__ float sPartQ[64][16];
  __shared__ float sMu[64];
  __shared__ float sRstd[64];
  int tid = threadIdx.x;
  int base = blockIdx.x * 64;
  const float4* h4 = (const float4*)(h + (size_t)base * H);
  const float4* a4 = (const float4*)(agg + (size_t)base * H);
#pragma unroll
  for (int it = 0; it < 4; it++) {  // all 64 rows (4096 float4)
    int vi = it * 1024 + tid;
    int row = vi >> 6, c4 = (vi & 63) * 4;
    float4 hv = h4[vi], av = a4[vi];
    uint2 uh;
    uh.x = pack2bf(hv.x + av.x, hv.y + av.y);
    uh.y = pack2bf(hv.z + av.z, hv.w + av.w);
    *(uint2*)&sAh[row * PITCH + c4] = uh;
  }
  __syncthreads();
  int lane = tid & 63, wv = tid >> 6;          // wv 0..15 = col-group
  int lane15 = lane & 15, quad = lane >> 4;
  int col = wv * 16 + lane15;                  // this thread's output column
  const unsigned short* aph = sAh + lane15 * PITCH + quad * 8;
  // ---- GEMM1: z1 = relu(z @ w1 + b1), acc[rg]
  f32x4 acc[4];
#pragma unroll
  for (int i = 0; i < 4; i++) acc[i] = (f32x4){0.f, 0.f, 0.f, 0.f};
  {
    const unsigned short* bph = w1Th + (size_t)col * H + quad * 8;
#pragma unroll
    for (int st = 0; st < 8; st++) {
      bf16x8 bhf = *(const bf16x8*)(bph + st * 32);
#pragma unroll
      for (int rg = 0; rg < 4; rg++) {
        bf16x8 ah = *(const bf16x8*)(aph + rg * 16 * PITCH + st * 32);
        acc[rg] = __builtin_amdgcn_mfma_f32_16x16x32_bf16(ah, bhf, acc[rg], 0, 0, 0);
      }
    }
  }
  float b1v = b1[col];
  __syncthreads();  // all waves done reading z
#pragma unroll
  for (int rg = 0; rg < 4; rg++)
#pragma unroll
    for (int r = 0; r < 4; r++) {
      int row = rg * 16 + quad * 4 + r;
      sAh[row * PITCH + col] = f2bf1(fmaxf(acc[rg][r] + b1v, 0.f));
    }
  __syncthreads();
  // ---- GEMM2: z2 = z1 @ w2 + b2, acc2[rg]
  f32x4 acc2[4];
#pragma unroll
  for (int i = 0; i < 4; i++) acc2[i] = (f32x4){0.f, 0.f, 0.f, 0.f};
  {
    const unsigned short* bph = w2Th + (size_t)col * H + quad * 8;
#pragma unroll
    for (int st = 0; st < 8; st++) {
      bf16x8 bhf = *(const bf16x8*)(bph + st * 32);
#pragma unroll
      for (int rg = 0; rg < 4; rg++) {
        bf16x8 ah = *(const bf16x8*)(aph + rg * 16 * PITCH + st * 32);
        acc2[rg] = __builtin_amdgcn_mfma_f32_16x16x32_bf16(ah, bhf, acc2[rg], 0, 0, 0);
      }
    }
  }
  float b2v = b2[col], gv = lng[col], bbv = lnb[col];
  // ---- LN partials: per row, reduce this wave's 16 cols
#pragma unroll
  for (int rg = 0; rg < 4; rg++)
#pragma unroll
    for (int r = 0; r < 4; r++) {
      int row = rg * 16 + quad * 4 + r;
      float z2 = acc2[rg][r] + b2v;
      float s = z2, ss = z2 * z2;
      s += __shfl_xor(s, 1, 64); ss += __shfl_xor(ss, 1, 64);
      s += __shfl_xor(s, 2, 64); ss += __shfl_xor(ss, 2, 64);
      s += __shfl_xor(s, 4, 64); ss += __shfl_xor(ss, 4, 64);
      s += __shfl_xor(s, 8, 64); ss += __shfl_xor(ss, 8, 64);
      if (lane15 == 0) { sPartS[row][wv] = s; sPartQ[row][wv] = ss; }
    }
  __syncthreads();
  if (tid < 64) {
    float s = 0.f, ss = 0.f;
#pragma unroll
    for (int w = 0; w < 16; w++) { s += sPartS[tid][w]; ss += sPartQ[tid][w]; }
    float mu = s * (1.f / H);
    float var = ss * (1.f / H) - mu * mu;
    sMu[tid] = mu;
    sRstd[tid] = rsqrtf(var + LN_EPS);
  }
  __syncthreads();
  // ---- apply LN + residual
  if (!last) {
#pragma unroll
    for (int rg = 0; rg < 4; rg++)
#pragma unroll
      for (int r = 0; r < 4; r++) {
        int row = rg * 16 + quad * 4 + r;
        float mu = sMu[row], rstd = sRstd[row];
        size_t o = (size_t)(base + row) * H + col;
        float z2 = acc2[rg][r] + b2v;
        float v = fmaf((z2 - mu) * rstd, gv, bbv);
        float hn = h[o] + fmaxf(v, 0.f);
        h[o] = hn;
        hbf[o] = f2bf1(hn);
      }
  } else {
    // fused mean-pool: block's 64 rows lie in one graph (64 | n)
    int bg = base / n;
    float psum = 0.f;
#pragma unroll
    for (int rg = 0; rg < 4; rg++)
#pragma unroll
      for (int r = 0; r < 4; r++) {
        int row = rg * 16 + quad * 4 + r;
        float mu = sMu[row], rstd = sRstd[row];
        size_t o = (size_t)(base + row) * H + col;
        float z2 = acc2[rg][r] + b2v;
        float v = fmaf((z2 - mu) * rstd, gv, bbv);
        psum += h[o] + fmaxf(v, 0.f);
      }
    atomicAdd(&g[(size_t)bg * H + col], psum);
  }
}

// Head MLP from pooled g. One block per graph.
__global__ __launch_bounds__(256) void k_head(
    const float* __restrict__ g,
    const float* __restrict__ w1, const float* __restrict__ b1,
    const float* __restrict__ w2, const float* __restrict__ b2,
    float* __restrict__ out, int n) {
  __shared__ float sG[H];
  __shared__ float sT[H];
  __shared__ float sR[4];
  int b = blockIdx.x, tid = threadIdx.x;
  sG[tid] = g[(size_t)b * H + tid] / (float)n;
  __syncthreads();
  float t = b1[tid];
  for (int k = 0; k < H; k++) t = fmaf(sG[k], w1[k * H + tid], t);
  sT[tid] = fmaxf(t, 0.f);
  __syncthreads();
  float p = sT[tid] * w2[tid];
#pragma unroll
  for (int off = 32; off > 0; off >>= 1) p += __shfl_xor(p, off, 64);
  if ((tid & 63) == 0) sR[tid >> 6] = p;
  __syncthreads();
  if (tid == 0) out[b] = sR[0] + sR[1] + sR[2] + sR[3] + b2[0];
}

// ---------- launcher ----------
extern "C" void kernel_launch(void* const* d_in, const int* in_sizes, int n_in,
                              void* d_out, int out_size, void* d_ws, size_t ws_size,
                              hipStream_t stream) {
  const float* x      = (const float*)d_in[0];
  const float* ea     = (const float*)d_in[1];
  const void*  ei     = d_in[2];
  const int*   a      = (const int*)d_in[3];
  const float* np_w   = (const float*)d_in[4];
  const float* np_b   = (const float*)d_in[5];
  const float* em_w1  = (const float*)d_in[6];
  const float* em_b1  = (const float*)d_in[7];
  const float* em_w2  = (const float*)d_in[8];
  const float* em_b2  = (const float*)d_in[9];
  const float* lin_w  = (const float*)d_in[10];
  const float* lin_b  = (const float*)d_in[11];
  const float* m_w1   = (const float*)d_in[12];
  const float* m_b1   = (const float*)d_in[13];
  const float* m_w2   = (const float*)d_in[14];
  const float* m_b2   = (const float*)d_in[15];
  const float* ln_g   = (const float*)d_in[16];
  const float* ln_b   = (const float*)d_in[17];
  const float* hd_w1  = (const float*)d_in[18];
  const float* hd_b1  = (const float*)d_in[19];
  const float* hd_w2  = (const float*)d_in[20];
  const float* hd_b2  = (const float*)d_in[21];

  int N = in_sizes[0] / 3;
  int E = in_sizes[1] / 4;
  int B = out_size;
  int n = N / B;

  // workspace layout
  char* ws = (char*)d_ws;
  size_t off = 0;
  auto alloc = [&](size_t bytes) {
    char* p = ws + off;
    off += (bytes + 255) & ~(size_t)255;
    return p;
  };
  float* h    = (float*)alloc((size_t)N * H * 4);
  unsigned short* hbf = (unsigned short*)alloc((size_t)N * H * 2);
  float* agg  = (float*)alloc((size_t)N * H * 4);
  unsigned short* wcTh = (unsigned short*)alloc((size_t)3 * H * H * 2);
  unsigned short* w1Th = (unsigned short*)alloc((size_t)3 * H * H * 2);
  unsigned short* w2Th = (unsigned short*)alloc((size_t)3 * H * H * 2);
  float* beta  = (float*)alloc(3 * H * 4);
  int*   hist  = (int*)alloc((size_t)N * 4);
  int*   curs  = (int*)alloc((size_t)N * 4);
  int*   srcS  = (int*)alloc((size_t)E * 4);
  int*   dstS  = (int*)alloc((size_t)E * 4);
  float* eaS   = (float*)alloc((size_t)E * 4 * 4);
  float* g     = (float*)alloc((size_t)B * H * 4);

  float* out = (float*)d_out;
  int ebl = (E + 255) / 256;

  hipMemsetAsync(hist, 0, (size_t)N * 4, stream);
  k_hist<<<ebl, 256, 0, stream>>>(ei, hist, E);
  k_scan<<<1, 256, 0, stream>>>(hist, curs, N);
  k_scatter<<<ebl, 256, 0, stream>>>(ei, ea, curs, srcS, dstS, eaS, E);
  k_node_proj<<<N, 256, 0, stream>>>(x, a, np_w, np_b, h, hbf, N);
  k_prep<<<123, 256, 0, stream>>>(em_w2, lin_w, lin_b, em_b2, m_w1, m_w2,
                                  wcTh, w1Th, w2Th, beta);

  hipMemsetAsync(g, 0, (size_t)B * H * 4, stream);
  for (int l = 0; l < 3; l++) {
    hipMemsetAsync(agg, 0, (size_t)N * H * 4, stream);
    k_edge_mfma<<<E / TE, 1024, 0, stream>>>(eaS, em_w1, em_b1,
                                             wcTh + (size_t)l * H * H,
                                             beta + (size_t)l * H,
                                             hbf, agg, srcS, dstS);
    k_node_mfma<<<N / 64, 1024, 0, stream>>>(h, hbf, agg,
                                             w1Th + (size_t)l * H * H,
                                             m_b1 + (size_t)l * H,
                                             w2Th + (size_t)l * H * H,
                                             m_b2 + (size_t)l * H,
                                             ln_g + (size_t)l * H, ln_b + (size_t)l * H,
                                             g, n, (l == 2) ? 1 : 0);
  }
  k_head<<<B, 256, 0, stream>>>(g, hd_w1, hd_b1, hd_w2, hd_b2, out, n);
}

// Round 20
// 839.313 us; speedup vs baseline: 1.0369x; 1.0049x over previous
//
#include <hip/hip_runtime.h>
#include <hip/hip_bf16.h>

#define H 256
#define LN_EPS 1e-5f
#define PITCH 264   // bf16 elements per LDS A-row (256 + 8 pad), 528 B
#define PITCHT 132  // bf16 elements per transposed elbuf col (128 + 4), 264 B
#define TE 128      // edges per tile (edge kernel)

typedef __attribute__((ext_vector_type(8))) short bf16x8;   // 8 bf16 = 4 VGPRs
typedef __attribute__((ext_vector_type(4))) float f32x4;    // MFMA 16x16 accum

// ---------- helpers ----------
__device__ __forceinline__ float bf2f(unsigned short u) {
  union { unsigned int i; float f; } v; v.i = ((unsigned int)u) << 16; return v.f;
}
// packed pair: low 16 = a, high 16 = b (RNE, single v_cvt_pk_bf16_f32)
__device__ __forceinline__ unsigned int pack2bf(float a, float b) {
  __hip_bfloat162 t = __float22bfloat162_rn(make_float2(a, b));
  unsigned int u;
  __builtin_memcpy(&u, &t, 4);
  return u;
}
// single value via the same HW cvt (1 instruction, RNE)
__device__ __forceinline__ unsigned short f2bf1(float a) {
  return (unsigned short)pack2bf(a, a);
}
// 64-bit edge_index detection: high words of first 4 long longs are zero
__device__ __forceinline__ int ei_is64(const void* ei) {
  const int* p = (const int*)ei;
  return (p[1] == 0 && p[3] == 0 && p[5] == 0 && p[7] == 0) ? 1 : 0;
}

// fp32 register-tiled GEMM core (precompute only)
__device__ __forceinline__ void gemm_tile(const float* __restrict__ sA,
                                          const float* __restrict__ W,
                                          int lane_j, int rg, float acc[8][4]) {
#pragma unroll
  for (int mm = 0; mm < 8; mm++)
#pragma unroll
    for (int cc = 0; cc < 4; cc++) acc[mm][cc] = 0.f;
  for (int k = 0; k < H; k += 4) {
    float tvf[8][4];
#pragma unroll
    for (int mm = 0; mm < 8; mm++)
      *(float4*)&tvf[mm][0] = *(const float4*)&sA[(rg * 8 + mm) * H + k];
#pragma unroll
    for (int kk = 0; kk < 4; kk++) {
      const float* wr = W + (k + kk) * H + lane_j;
      float w0 = wr[0], w1 = wr[64], w2 = wr[128], w3 = wr[192];
#pragma unroll
      for (int mm = 0; mm < 8; mm++) {
        float av = tvf[mm][kk];
        acc[mm][0] = fmaf(av, w0, acc[mm][0]);
        acc[mm][1] = fmaf(av, w1, acc[mm][1]);
        acc[mm][2] = fmaf(av, w2, acc[mm][2]);
        acc[mm][3] = fmaf(av, w3, acc[mm][3]);
      }
    }
  }
}

// ---------- precompute kernels ----------

// dst histogram (inline 64-bit detection; uniform branch, L2-cached reads)
__global__ __launch_bounds__(256) void k_hist(
    const void* __restrict__ ei, int* __restrict__ hist, int E) {
  int e = blockIdx.x * 256 + threadIdx.x;
  if (e >= E) return;
  int d = ei_is64(ei) ? (int)((const long long*)ei)[(size_t)E + e]
                      : ((const int*)ei)[(size_t)E + e];
  atomicAdd(&hist[d], 1);
}

// exclusive prefix sum over hist[N] -> cursor[N] (single block, 256 threads)
__global__ __launch_bounds__(256) void k_scan(
    const int* __restrict__ hist, int* __restrict__ cursor, int N) {
  __shared__ int part[256];
  int tid = threadIdx.x;
  int chunk = (N + 255) / 256;
  int s = 0;
  for (int i = 0; i < chunk; i++) {
    int idx = tid * chunk + i;
    if (idx < N) s += hist[idx];
  }
  part[tid] = s;
  __syncthreads();
  for (int off = 1; off < 256; off <<= 1) {
    int v = (tid >= off) ? part[tid - off] : 0;
    __syncthreads();
    part[tid] += v;
    __syncthreads();
  }
  int excl = (tid == 0) ? 0 : part[tid - 1];
  for (int i = 0; i < chunk; i++) {
    int idx = tid * chunk + i;
    if (idx < N) {
      cursor[idx] = excl;
      excl += hist[idx];
    }
  }
}

// scatter edges into dst-sorted order (src, dst, edge_attr)
__global__ __launch_bounds__(256) void k_scatter(
    const void* __restrict__ ei,
    const float* __restrict__ ea, int* __restrict__ cursor,
    int* __restrict__ srcS, int* __restrict__ dstS, float* __restrict__ eaS, int E) {
  int e = blockIdx.x * 256 + threadIdx.x;
  if (e >= E) return;
  int is64 = ei_is64(ei);
  int s = is64 ? (int)((const long long*)ei)[e] : ((const int*)ei)[e];
  int d = is64 ? (int)((const long long*)ei)[(size_t)E + e]
               : ((const int*)ei)[(size_t)E + e];
  int p = atomicAdd(&cursor[d], 1);
  srcS[p] = s;
  dstS[p] = d;
  ((float4*)eaS)[p] = ((const float4*)ea)[e];
}

// R20: 64 nodes per block (512 blocks vs 32768). Thread = column; weight
// row hoisted to registers once; 64 independent iterations. Same fma order
// as before -> bit-identical h/hbf. Kills per-node block setup churn and
// 64x weight re-reads.
__global__ __launch_bounds__(256) void k_node_proj(
    const float* __restrict__ x, const int* __restrict__ a,
    const float* __restrict__ w, const float* __restrict__ b,
    float* __restrict__ h, unsigned short* __restrict__ hbf, int N) {
  int j = threadIdx.x;
  int n0 = blockIdx.x * 64;
  float w0 = w[0 * H + j], w1v = w[1 * H + j];
  float w2v = w[2 * H + j], w3v = w[3 * H + j];
  float bb = b[j];
#pragma unroll 4
  for (int i = 0; i < 64; i++) {
    int node = n0 + i;
    float acc = bb;
    acc = fmaf(x[node * 3 + 0], w0, acc);
    acc = fmaf(x[node * 3 + 1], w1v, acc);
    acc = fmaf(x[node * 3 + 2], w2v, acc);
    acc = fmaf((float)a[node], w3v, acc);
    float v = fmaxf(acc, 0.f);
    h[(size_t)node * H + j] = v;
    hbf[(size_t)node * H + j] = f2bf1(v);
  }
}

// merged precompute: one dispatch, per-block uniform path.
//   bid  0..23 : wcomb  (WtC[l][j][k] = (em_w2 @ lin_w[l])[k][j], bf16 hi)
//   bid 24..26 : beta   (beta[l] = em_b2 @ lin_w[l] + lin_b[l])
//   bid 27..74 : transp m_w1 -> w1Th  (out[l][n][k] = bf16(in[l][k][n]))
//   bid 75..122: transp m_w2 -> w2Th
__global__ __launch_bounds__(256, 2) void k_prep(
    const float* __restrict__ em_w2, const float* __restrict__ lin_w,
    const float* __restrict__ lin_b, const float* __restrict__ em_b2,
    const float* __restrict__ m_w1, const float* __restrict__ m_w2,
    unsigned short* __restrict__ wcTh, unsigned short* __restrict__ w1Th,
    unsigned short* __restrict__ w2Th, float* __restrict__ beta) {
  __shared__ __align__(16) float sBuf[32 * H];   // 32768 B
  int bid = blockIdx.x;
  int tid = threadIdx.x;
  if (bid < 24) {
    int l = bid >> 3, tile = bid & 7;
    const float4* src = (const float4*)(em_w2 + (size_t)tile * 32 * H);
#pragma unroll
    for (int it = 0; it < 8; it++) {
      int vi = it * 256 + tid;
      *(float4*)&sBuf[vi * 4] = src[vi];
    }
    __syncthreads();
    int lane_j = tid & 63, rg = tid >> 6;
    float acc[8][4];
    gemm_tile(sBuf, lin_w + (size_t)l * H * H, lane_j, rg, acc);
    unsigned short* oh = wcTh + (size_t)l * H * H;
#pragma unroll
    for (int cc = 0; cc < 4; cc++) {
      int j = lane_j + 64 * cc;
#pragma unroll
      for (int mm = 0; mm < 8; mm++) {
        int k = tile * 32 + rg * 8 + mm;
        oh[(size_t)j * H + k] = f2bf1(acc[mm][cc]);
      }
    }
  } else if (bid < 27) {
    int l = bid - 24, j = tid;
    const float* W = lin_w + (size_t)l * H * H;
    float v = lin_b[l * H + j];
    for (int k = 0; k < H; k++) v = fmaf(em_b2[k], W[k * H + j], v);
    beta[l * H + j] = v;
  } else {
    int idx = bid - 27;
    const float* in = m_w1;
    unsigned short* outp = w1Th;
    if (idx >= 48) { idx -= 48; in = m_w2; outp = w2Th; }
    int l = idx >> 4, rem = idx & 15;
    int kb = (rem & 3) * 64, nb = (rem >> 2) * 64;
    float (*T)[65] = (float(*)[65])sBuf;         // 16640 B < 32768 B
    const float* src = in + (size_t)l * H * H;
#pragma unroll
    for (int it = 0; it < 16; it++) {
      int i2 = it * 256 + tid;
      int kl = i2 >> 6, nl = i2 & 63;
      T[kl][nl] = src[(size_t)(kb + kl) * H + nb + nl];
    }
    __syncthreads();
    unsigned short* dh = outp + (size_t)l * H * H;
#pragma unroll
    for (int it = 0; it < 8; it++) {
      int u = it * 256 + tid;
      int nl = u >> 5, k2 = (u & 31) * 2;
      size_t o = (size_t)(nb + nl) * H + kb + k2;
      *(unsigned int*)&dh[o] = pack2bf(T[k2][nl], T[k2 + 1][nl]);
    }
  }
}

// ---------- per-layer MFMA kernels ----------

// Edge (dst-sorted), tile = TE(128) edges x 256 cols, 16 waves x 1024 thr.
// Wave owns ONE col-group x ALL 8 row-groups: acc[8]=32 regs, single
// ah/bhf live -> 64-reg cap of (1024,8) holds -> 2 blk/CU = 32 waves.
// Epilogue windows: R10's 4x(32-row x 1-col) form (R11/R12/R14 resplits all
// raised atomic RMW traffic and regressed -- do not re-split).
// Transposed bf16 elbuf [col][PITCHT] aliasing the A-tile (R17): writer
// packs each rg's 4 row-consecutive values into one b64; scatter preloads
// its contiguous 32-row column slice as 8 b64. Verified 158->153 us.
__global__ __launch_bounds__(1024, 8) void k_edge_mfma(
    const float* __restrict__ eaS,
    const float* __restrict__ w1, const float* __restrict__ b1,
    const unsigned short* __restrict__ Wth,
    const float* __restrict__ beta,
    const unsigned short* __restrict__ hbf, float* __restrict__ agg,
    const int* __restrict__ srcS, const int* __restrict__ dstS) {
  __shared__ __align__(16) unsigned short sAh[TE * PITCH];  // 67584 B, A-tile / elbufT
  __shared__ __align__(16) float sEA[TE * 4];               // 2048 B
  __shared__ int sSrc[TE];
  __shared__ int sDst[TE];
  int tid = threadIdx.x;
  int base = blockIdx.x * TE;
  if (tid < TE) {
    sSrc[tid] = srcS[base + tid];
  } else if (tid < 2 * TE) {
    sDst[tid - TE] = dstS[base + tid - TE];
  } else if (tid < 3 * TE) {
    int t = tid - 2 * TE;
    ((float4*)sEA)[t] = ((const float4*)(eaS + (size_t)base * 4))[t];
  }
  __syncthreads();
  {  // t = relu(eaS @ w1 + b1) -> bf16 hi plane (col pair, 16 rows/thread)
    int j2 = (tid & 127) * 2;
    int r0 = (tid >> 7) * 16;          // 8 groups x 16 rows = 128 rows
    float wv0[4], wv1[4];
#pragma unroll
    for (int q = 0; q < 4; q++) { wv0[q] = w1[q * H + j2]; wv1[q] = w1[q * H + j2 + 1]; }
    float bb0 = b1[j2], bb1 = b1[j2 + 1];
#pragma unroll
    for (int m = r0; m < r0 + 16; m++) {
      float4 e4 = *(const float4*)&sEA[m * 4];   // one b128 read per row
      float t0 = fmaf(e4.x, wv0[0], bb0);
      float t1 = fmaf(e4.x, wv1[0], bb1);
      t0 = fmaf(e4.y, wv0[1], t0);  t1 = fmaf(e4.y, wv1[1], t1);
      t0 = fmaf(e4.z, wv0[2], t0);  t1 = fmaf(e4.z, wv1[2], t1);
      t0 = fmaf(e4.w, wv0[3], t0);  t1 = fmaf(e4.w, wv1[3], t1);
      *(unsigned int*)&sAh[m * PITCH + j2] = pack2bf(fmaxf(t0, 0.f), fmaxf(t1, 0.f));
    }
  }
  __syncthreads();
  int lane = tid & 63, wv = tid >> 6;           // wv in 0..15 = col-group
  int lane15 = lane & 15, quad = lane >> 4;
  f32x4 acc[8];
#pragma unroll
  for (int i = 0; i < 8; i++) acc[i] = (f32x4){0.f, 0.f, 0.f, 0.f};
  const unsigned short* aph = sAh + lane15 * PITCH + quad * 8;
  const unsigned short* bph = Wth + (size_t)(wv * 16 + lane15) * H + quad * 8;
#pragma unroll
  for (int st = 0; st < 8; st++) {
    bf16x8 bhf = *(const bf16x8*)(bph + st * 32);
#pragma unroll
    for (int rg = 0; rg < 8; rg++) {
      bf16x8 ah = *(const bf16x8*)(aph + rg * 16 * PITCH + st * 32);
      acc[rg] = __builtin_amdgcn_mfma_f32_16x16x32_bf16(ah, bhf, acc[rg], 0, 0, 0);
    }
  }
  float bv = beta[wv * 16 + lane15];
  __syncthreads();  // all waves done reading A; sAh becomes TRANSPOSED elbuf
  // elbufT write: col = wv*16+lane15; rows rg*16+quad*4..+3 are consecutive
  // -> one b64 per rg (2 cvt_pk). acc dies here (never co-live with hvp).
  {
    int col = wv * 16 + lane15;
#pragma unroll
    for (int rg = 0; rg < 8; rg++) {
      uint2 wq;
      wq.x = pack2bf(acc[rg][0] + bv, acc[rg][1] + bv);
      wq.y = pack2bf(acc[rg][2] + bv, acc[rg][3] + bv);
      *(uint2*)&sAh[col * PITCHT + rg * 16 + quad * 4] = wq;
    }
  }
  // coalesced bf16 h-gather: one contiguous 128B run per row per wave;
  // pairs packed with one lshl_or each. Loads drain under the barrier.
  int jcol = tid & 255, quarter = tid >> 8;
  const int* msrc = sSrc + quarter * 32;
  unsigned int hvp[16];
#pragma unroll
  for (int p = 0; p < 16; p++) {
    unsigned int u0 = hbf[(size_t)msrc[2 * p] * H + jcol];
    unsigned int u1 = hbf[(size_t)msrc[2 * p + 1] * H + jcol];
    hvp[p] = u0 | (u1 << 16);
  }
  __syncthreads();
  // scatter: preload this thread's contiguous 32-row column slice (8 b64),
  // then segment-sum over the 32 dst-sorted rows.
  {
    unsigned int ev[16];
#pragma unroll
    for (int k = 0; k < 8; k++)
      *(uint2*)&ev[k * 2] = *(const uint2*)&sAh[jcol * PITCHT + quarter * 32 + k * 4];
    const int* mdst = sDst + quarter * 32;
    float run = 0.f;
    int prev = mdst[0];
#pragma unroll
    for (int m = 0; m < 32; m++) {
      int d = mdst[m];
      unsigned int hp = hvp[m >> 1];
      unsigned short hu = (m & 1) ? (unsigned short)(hp >> 16) : (unsigned short)hp;
      unsigned int ep = ev[m >> 1];
      unsigned short eu = (m & 1) ? (unsigned short)(ep >> 16) : (unsigned short)ep;
      float msg = fmaxf(bf2f(hu) + bf2f(eu), 0.f);
      if (d != prev) {
        atomicAdd(&agg[(size_t)prev * H + jcol], run);
        run = 0.f;
        prev = d;
      }
      run += msg;
    }
    atomicAdd(&agg[(size_t)prev * H + jcol], run);
  }
}

// Node: z=h+agg; z1=relu(z@w1+b1); z2=z1@w2+b2; LN; h += relu(LN).
// 64-row tile, 1024 thr x 16 waves, wave owns ONE 16-col group x ALL 4
// row-groups -> acc[4]=16 regs -> fits 64-reg cap of (1024,8) -> 32 waves/CU.
// last==1 fuses the mean-pool -- thread sums its 16 rows' hn and does one
// atomicAdd into g[graph][col]; h/hbf writes skipped (final h unused).
__global__ __launch_bounds__(1024, 8) void k_node_mfma(
    float* __restrict__ h, unsigned short* __restrict__ hbf,
    const float* __restrict__ agg,
    const unsigned short* __restrict__ w1Th, const float* __restrict__ b1,
    const unsigned short* __restrict__ w2Th, const float* __restrict__ b2,
    const float* __restrict__ lng, const float* __restrict__ lnb,
    float* __restrict__ g, int n, int last) {
  __shared__ __align__(16) unsigned short sAh[64 * PITCH];  // 33792 B
  __shared__ float sPartS[64][16];
  __shared__ float sPartQ[64][16];
  __shared__ float sMu[64];
  __shared__ float sRstd[64];
  int tid = threadIdx.x;
  int base = blockIdx.x * 64;
  const float4* h4 = (const float4*)(h + (size_t)base * H);
  const float4* a4 = (const float4*)(agg + (size_t)base * H);
#pragma unroll
  for (int it = 0; it < 4; it++) {  // all 64 rows (4096 float4)
    int vi = it * 1024 + tid;
    int row = vi >> 6, c4 = (vi & 63) * 4;
    float4 hv = h4[vi], av = a4[vi];
    uint2 uh;
    uh.x = pack2bf(hv.x + av.x, hv.y + av.y);
    uh.y = pack2bf(hv.z + av.z, hv.w + av.w);
    *(uint2*)&sAh[row * PITCH + c4] = uh;
  }
  __syncthreads();
  int lane = tid & 63, wv = tid >> 6;          // wv 0..15 = col-group
  int lane15 = lane & 15, quad = lane >> 4;
  int col = wv * 16 + lane15;                  // this thread's output column
  const unsigned short* aph = sAh + lane15 * PITCH + quad * 8;
  // ---- GEMM1: z1 = relu(z @ w1 + b1), acc[rg]
  f32x4 acc[4];
#pragma unroll
  for (int i = 0; i < 4; i++) acc[i] = (f32x4){0.f, 0.f, 0.f, 0.f};
  {
    const unsigned short* bph = w1Th + (size_t)col * H + quad * 8;
#pragma unroll
    for (int st = 0; st < 8; st++) {
      bf16x8 bhf = *(const bf16x8*)(bph + st * 32);
#pragma unroll
      for (int rg = 0; rg < 4; rg++) {
        bf16x8 ah = *(const bf16x8*)(aph + rg * 16 * PITCH + st * 32);
        acc[rg] = __builtin_amdgcn_mfma_f32_16x16x32_bf16(ah, bhf, acc[rg], 0, 0, 0);
      }
    }
  }
  float b1v = b1[col];
  __syncthreads();  // all waves done reading z
#pragma unroll
  for (int rg = 0; rg < 4; rg++)
#pragma unroll
    for (int r = 0; r < 4; r++) {
      int row = rg * 16 + quad * 4 + r;
      sAh[row * PITCH + col] = f2bf1(fmaxf(acc[rg][r] + b1v, 0.f));
    }
  __syncthreads();
  // ---- GEMM2: z2 = z1 @ w2 + b2, acc2[rg]
  f32x4 acc2[4];
#pragma unroll
  for (int i = 0; i < 4; i++) acc2[i] = (f32x4){0.f, 0.f, 0.f, 0.f};
  {
    const unsigned short* bph = w2Th + (size_t)col * H + quad * 8;
#pragma unroll
    for (int st = 0; st < 8; st++) {
      bf16x8 bhf = *(const bf16x8*)(bph + st * 32);
#pragma unroll
      for (int rg = 0; rg < 4; rg++) {
        bf16x8 ah = *(const bf16x8*)(aph + rg * 16 * PITCH + st * 32);
        acc2[rg] = __builtin_amdgcn_mfma_f32_16x16x32_bf16(ah, bhf, acc2[rg], 0, 0, 0);
      }
    }
  }
  float b2v = b2[col], gv = lng[col], bbv = lnb[col];
  // ---- LN partials: per row, reduce this wave's 16 cols
#pragma unroll
  for (int rg = 0; rg < 4; rg++)
#pragma unroll
    for (int r = 0; r < 4; r++) {
      int row = rg * 16 + quad * 4 + r;
      float z2 = acc2[rg][r] + b2v;
      float s = z2, ss = z2 * z2;
      s += __shfl_xor(s, 1, 64); ss += __shfl_xor(ss, 1, 64);
      s += __shfl_xor(s, 2, 64); ss += __shfl_xor(ss, 2, 64);
      s += __shfl_xor(s, 4, 64); ss += __shfl_xor(ss, 4, 64);
      s += __shfl_xor(s, 8, 64); ss += __shfl_xor(ss, 8, 64);
      if (lane15 == 0) { sPartS[row][wv] = s; sPartQ[row][wv] = ss; }
    }
  __syncthreads();
  if (tid < 64) {
    float s = 0.f, ss = 0.f;
#pragma unroll
    for (int w = 0; w < 16; w++) { s += sPartS[tid][w]; ss += sPartQ[tid][w]; }
    float mu = s * (1.f / H);
    float var = ss * (1.f / H) - mu * mu;
    sMu[tid] = mu;
    sRstd[tid] = rsqrtf(var + LN_EPS);
  }
  __syncthreads();
  // ---- apply LN + residual
  if (!last) {
#pragma unroll
    for (int rg = 0; rg < 4; rg++)
#pragma unroll
      for (int r = 0; r < 4; r++) {
        int row = rg * 16 + quad * 4 + r;
        float mu = sMu[row], rstd = sRstd[row];
        size_t o = (size_t)(base + row) * H + col;
        float z2 = acc2[rg][r] + b2v;
        float v = fmaf((z2 - mu) * rstd, gv, bbv);
        float hn = h[o] + fmaxf(v, 0.f);
        h[o] = hn;
        hbf[o] = f2bf1(hn);
      }
  } else {
    // fused mean-pool: block's 64 rows lie in one graph (64 | n)
    int bg = base / n;
    float psum = 0.f;
#pragma unroll
    for (int rg = 0; rg < 4; rg++)
#pragma unroll
      for (int r = 0; r < 4; r++) {
        int row = rg * 16 + quad * 4 + r;
        float mu = sMu[row], rstd = sRstd[row];
        size_t o = (size_t)(base + row) * H + col;
        float z2 = acc2[rg][r] + b2v;
        float v = fmaf((z2 - mu) * rstd, gv, bbv);
        psum += h[o] + fmaxf(v, 0.f);
      }
    atomicAdd(&g[(size_t)bg * H + col], psum);
  }
}

// Head MLP from pooled g. One block per graph.
__global__ __launch_bounds__(256) void k_head(
    const float* __restrict__ g,
    const float* __restrict__ w1, const float* __restrict__ b1,
    const float* __restrict__ w2, const float* __restrict__ b2,
    float* __restrict__ out, int n) {
  __shared__ float sG[H];
  __shared__ float sT[H];
  __shared__ float sR[4];
  int b = blockIdx.x, tid = threadIdx.x;
  sG[tid] = g[(size_t)b * H + tid] / (float)n;
  __syncthreads();
  float t = b1[tid];
  for (int k = 0; k < H; k++) t = fmaf(sG[k], w1[k * H + tid], t);
  sT[tid] = fmaxf(t, 0.f);
  __syncthreads();
  float p = sT[tid] * w2[tid];
#pragma unroll
  for (int off = 32; off > 0; off >>= 1) p += __shfl_xor(p, off, 64);
  if ((tid & 63) == 0) sR[tid >> 6] = p;
  __syncthreads();
  if (tid == 0) out[b] = sR[0] + sR[1] + sR[2] + sR[3] + b2[0];
}

// ---------- launcher ----------
extern "C" void kernel_launch(void* const* d_in, const int* in_sizes, int n_in,
                              void* d_out, int out_size, void* d_ws, size_t ws_size,
                              hipStream_t stream) {
  const float* x      = (const float*)d_in[0];
  const float* ea     = (const float*)d_in[1];
  const void*  ei     = d_in[2];
  const int*   a      = (const int*)d_in[3];
  const float* np_w   = (const float*)d_in[4];
  const float* np_b   = (const float*)d_in[5];
  const float* em_w1  = (const float*)d_in[6];
  const float* em_b1  = (const float*)d_in[7];
  const float* em_w2  = (const float*)d_in[8];
  const float* em_b2  = (const float*)d_in[9];
  const float* lin_w  = (const float*)d_in[10];
  const float* lin_b  = (const float*)d_in[11];
  const float* m_w1   = (const float*)d_in[12];
  const float* m_b1   = (const float*)d_in[13];
  const float* m_w2   = (const float*)d_in[14];
  const float* m_b2   = (const float*)d_in[15];
  const float* ln_g   = (const float*)d_in[16];
  const float* ln_b   = (const float*)d_in[17];
  const float* hd_w1  = (const float*)d_in[18];
  const float* hd_b1  = (const float*)d_in[19];
  const float* hd_w2  = (const float*)d_in[20];
  const float* hd_b2  = (const float*)d_in[21];

  int N = in_sizes[0] / 3;
  int E = in_sizes[1] / 4;
  int B = out_size;
  int n = N / B;

  // workspace layout
  char* ws = (char*)d_ws;
  size_t off = 0;
  auto alloc = [&](size_t bytes) {
    char* p = ws + off;
    off += (bytes + 255) & ~(size_t)255;
    return p;
  };
  float* h    = (float*)alloc((size_t)N * H * 4);
  unsigned short* hbf = (unsigned short*)alloc((size_t)N * H * 2);
  float* agg  = (float*)alloc((size_t)N * H * 4);
  unsigned short* wcTh = (unsigned short*)alloc((size_t)3 * H * H * 2);
  unsigned short* w1Th = (unsigned short*)alloc((size_t)3 * H * H * 2);
  unsigned short* w2Th = (unsigned short*)alloc((size_t)3 * H * H * 2);
  float* beta  = (float*)alloc(3 * H * 4);
  int*   hist  = (int*)alloc((size_t)N * 4);
  int*   curs  = (int*)alloc((size_t)N * 4);
  int*   srcS  = (int*)alloc((size_t)E * 4);
  int*   dstS  = (int*)alloc((size_t)E * 4);
  float* eaS   = (float*)alloc((size_t)E * 4 * 4);
  float* g     = (float*)alloc((size_t)B * H * 4);

  float* out = (float*)d_out;
  int ebl = (E + 255) / 256;

  hipMemsetAsync(hist, 0, (size_t)N * 4, stream);
  k_hist<<<ebl, 256, 0, stream>>>(ei, hist, E);
  k_scan<<<1, 256, 0, stream>>>(hist, curs, N);
  k_scatter<<<ebl, 256, 0, stream>>>(ei, ea, curs, srcS, dstS, eaS, E);
  k_node_proj<<<N / 64, 256, 0, stream>>>(x, a, np_w, np_b, h, hbf, N);
  k_prep<<<123, 256, 0, stream>>>(em_w2, lin_w, lin_b, em_b2, m_w1, m_w2,
                                  wcTh, w1Th, w2Th, beta);

  hipMemsetAsync(g, 0, (size_t)B * H * 4, stream);
  for (int l = 0; l < 3; l++) {
    hipMemsetAsync(agg, 0, (size_t)N * H * 4, stream);
    k_edge_mfma<<<E / TE, 1024, 0, stream>>>(eaS, em_w1, em_b1,
                                             wcTh + (size_t)l * H * H,
                                             beta + (size_t)l * H,
                                             hbf, agg, srcS, dstS);
    k_node_mfma<<<N / 64, 1024, 0, stream>>>(h, hbf, agg,
                                             w1Th + (size_t)l * H * H,
                                             m_b1 + (size_t)l * H,
                                             w2Th + (size_t)l * H * H,
                                             m_b2 + (size_t)l * H,
                                             ln_g + (size_t)l * H, ln_b + (size_t)l * H,
                                             g, n, (l == 2) ? 1 : 0);
  }
  k_head<<<B, 256, 0, stream>>>(g, hd_w1, hd_b1, hd_w2, hd_b2, out, n);
}